// Round 3
// baseline (294.465 us; speedup 1.0000x reference)
//
#include <hip/hip_runtime.h>
#include <math.h>

// Problem constants
#define BB 2
#define LL 1024
#define HH 1024
#define NH 16
#define DD 64
#define HD (NH * DD)   // 1024
#define MM (BB * LL)   // 2048
#define RCT 32         // recurrence chunk length staged in LDS
#define KEXT 3072      // extended K for f16 hi/lo split GEMM (3 x 1024)
#define NBK 1088       // k-GEMM B rows: 1024 k + 16 alpha + 16 beta + 32 pad

typedef _Float16 f16x8 __attribute__((ext_vector_type(8)));
typedef _Float16 f16x4 __attribute__((ext_vector_type(4)));
typedef float f32x4 __attribute__((ext_vector_type(4)));

// ---------------------------------------------------------------------------
// async global->LDS, 16B per lane; LDS dest = wave-uniform base + lane*16
// ---------------------------------------------------------------------------
__device__ __forceinline__ void load_lds16(const void* g, void* l) {
    __builtin_amdgcn_global_load_lds(
        (const __attribute__((address_space(1))) void*)g,
        (__attribute__((address_space(3))) void*)l, 16, 0, 0);
}

// ---------------------------------------------------------------------------
// Conversions. Only k/alpha/beta compound through the recurrence -> 3-split
// f16 (K=3072); q (readout) and v (additive) are plain f16 and read the hi
// section of Ae3 directly (row stride KEXT) — no separate Ah copy.
//   blocks [0,2048):        hs -> Ae3 (x16, [hi|lo|hi])
//   blocks [2048,3136):     Wk/Wa/Wb -> Bk (x64, [hi|hi|lo]), rows>=1056 zero
//   blocks [3136,5184):     Wq|Wv -> Bqv (x64, hi only)
//   blocks [5184,6208):     Wo -> Be2 (x64, hi only)
// ---------------------------------------------------------------------------
__global__ __launch_bounds__(256) void convert_front(
    const float* __restrict__ hs,
    const float* __restrict__ Wq, const float* __restrict__ Wk,
    const float* __restrict__ Wv, const float* __restrict__ Wa,
    const float* __restrict__ Wb, const float* __restrict__ Wo,
    _Float16* __restrict__ Ae3,
    _Float16* __restrict__ Bk, _Float16* __restrict__ Bqv,
    _Float16* __restrict__ Be2)
{
    const int blk = blockIdx.x;
    const int t = threadIdx.x;

    if (blk < 2048) {             // hs -> Ae3 (3-split)
        float4 x = *(const float4*)(hs + (size_t)blk * 1024 + t * 4);
        x.x *= 16.f; x.y *= 16.f; x.z *= 16.f; x.w *= 16.f;
        f16x4 h, l;
        h[0] = (_Float16)x.x; l[0] = (_Float16)(x.x - (float)h[0]);
        h[1] = (_Float16)x.y; l[1] = (_Float16)(x.y - (float)h[1]);
        h[2] = (_Float16)x.z; l[2] = (_Float16)(x.z - (float)h[2]);
        h[3] = (_Float16)x.w; l[3] = (_Float16)(x.w - (float)h[3]);
        _Float16* base = Ae3 + (size_t)blk * KEXT + t * 4;
        *(f16x4*)(base)        = h;
        *(f16x4*)(base + 1024) = l;
        *(f16x4*)(base + 2048) = h;
        return;
    }
    if (blk < 3136) {             // Wk/Wa/Wb -> Bk (3-split, B-order)
        const int n = blk - 2048;
        const float* src = nullptr;
        if (n < 1024)      src = Wk + (size_t)n * 1024;
        else if (n < 1040) src = Wa + (size_t)(n - 1024) * 1024;
        else if (n < 1056) src = Wb + (size_t)(n - 1040) * 1024;
        float4 x = src ? *(const float4*)(src + t * 4)
                       : make_float4(0.f, 0.f, 0.f, 0.f);
        x.x *= 64.f; x.y *= 64.f; x.z *= 64.f; x.w *= 64.f;
        f16x4 h, l;
        h[0] = (_Float16)x.x; l[0] = (_Float16)(x.x - (float)h[0]);
        h[1] = (_Float16)x.y; l[1] = (_Float16)(x.y - (float)h[1]);
        h[2] = (_Float16)x.z; l[2] = (_Float16)(x.z - (float)h[2]);
        h[3] = (_Float16)x.w; l[3] = (_Float16)(x.w - (float)h[3]);
        _Float16* base = Bk + (size_t)n * KEXT + t * 4;
        *(f16x4*)(base)        = h;
        *(f16x4*)(base + 1024) = h;
        *(f16x4*)(base + 2048) = l;
        return;
    }
    if (blk < 5184) {             // Wq|Wv -> Bqv (hi only)
        const int n = blk - 3136;
        const float* src = (n < 1024) ? Wq + (size_t)n * 1024
                                      : Wv + (size_t)(n - 1024) * 1024;
        float4 x = *(const float4*)(src + t * 4);
        f16x4 h;
        h[0] = (_Float16)(x.x * 64.f);
        h[1] = (_Float16)(x.y * 64.f);
        h[2] = (_Float16)(x.z * 64.f);
        h[3] = (_Float16)(x.w * 64.f);
        *(f16x4*)(Bqv + (size_t)n * 1024 + t * 4) = h;
        return;
    }
    {                             // Wo -> Be2 (hi only)
        const int n = blk - 5184;
        float4 x = *(const float4*)(Wo + (size_t)n * 1024 + t * 4);
        f16x4 h;
        h[0] = (_Float16)(x.x * 64.f);
        h[1] = (_Float16)(x.y * 64.f);
        h[2] = (_Float16)(x.z * 64.f);
        h[3] = (_Float16)(x.w * 64.f);
        *(f16x4*)(Be2 + (size_t)n * 1024 + t * 4) = h;
    }
}

// ---------------------------------------------------------------------------
// MERGED projection GEMM: 528 blocks.
//   blk <  272: k+ab part — Ae3 @ Bk^T, K=3072, 128x64 tile (17 N-tiles).
//   blk >= 272: q|v part  — Ae3-hi @ Bqv^T, K=1024, 128x128 tile (A row
//               stride KEXT, hi section).
// ---------------------------------------------------------------------------
__global__ __launch_bounds__(256) void mfma_gemm_proj(
    const _Float16* __restrict__ Ae3, const _Float16* __restrict__ Bk,
    const _Float16* __restrict__ Bqv,
    float* __restrict__ qkv, float* __restrict__ ab,
    const float* __restrict__ bq, const float* __restrict__ bk,
    const float* __restrict__ bv)
{
    __shared__ __align__(16) _Float16 As[2][128 * 32];
    __shared__ __align__(16) _Float16 Bs[2][128 * 32];

    const int blk = blockIdx.x;
    const int tid = threadIdx.x;
    const int wave = tid >> 6;
    const int lane = tid & 63;
    const int srow = lane >> 2;
    const int scol = (lane & 3) * 8;
    const int fm = lane & 15;
    const int fq = (lane >> 4) * 8;
    const int rquad = (lane >> 4) * 4;

    if (blk < 272) {
        const int bm = (blk / 17) * 128;
        const int bn = (blk % 17) * 64;
        const int wr = (wave >> 1) * 64;
        const int wc = (wave & 1) * 32;

        const _Float16* gA0 = Ae3 + (size_t)(bm + wave * 32 + srow) * KEXT + scol;
        const _Float16* gA1 = gA0 + (size_t)16 * KEXT;
        const _Float16* gB0 = Bk + (size_t)(bn + wave * 16 + srow) * KEXT + scol;
        _Float16* lA0_0 = &As[0][(wave * 32) * 32];
        _Float16* lA1_0 = &As[0][(wave * 32 + 16) * 32];
        _Float16* lB0_0 = &Bs[0][(wave * 16) * 32];
        _Float16* lA0_1 = &As[1][(wave * 32) * 32];
        _Float16* lA1_1 = &As[1][(wave * 32 + 16) * 32];
        _Float16* lB0_1 = &Bs[1][(wave * 16) * 32];

        f32x4 acc[4][2] = {};

        for (int k0 = 0; k0 < KEXT; k0 += 64) {
            load_lds16(gA0 + k0,      lA0_0);
            load_lds16(gA1 + k0,      lA1_0);
            load_lds16(gB0 + k0,      lB0_0);
            load_lds16(gA0 + k0 + 32, lA0_1);
            load_lds16(gA1 + k0 + 32, lA1_1);
            load_lds16(gB0 + k0 + 32, lB0_1);
            __syncthreads();

            #pragma unroll
            for (int s = 0; s < 2; ++s) {
                f16x8 a[4], b[2];
                #pragma unroll
                for (int mt = 0; mt < 4; ++mt)
                    a[mt] = *(const f16x8*)&As[s][(wr + mt * 16 + fm) * 32 + fq];
                #pragma unroll
                for (int nt = 0; nt < 2; ++nt)
                    b[nt] = *(const f16x8*)&Bs[s][(wc + nt * 16 + fm) * 32 + fq];
                #pragma unroll
                for (int mt = 0; mt < 4; ++mt)
                    #pragma unroll
                    for (int nt = 0; nt < 2; ++nt)
                        acc[mt][nt] = __builtin_amdgcn_mfma_f32_16x16x32_f16(
                            a[mt], b[nt], acc[mt][nt], 0, 0, 0);
            }
            __syncthreads();
        }

        #pragma unroll
        for (int mt = 0; mt < 4; ++mt) {
            #pragma unroll
            for (int nt = 0; nt < 2; ++nt) {
                const int col = bn + wc + nt * 16 + fm;
                #pragma unroll
                for (int i = 0; i < 4; ++i) {
                    const int row = bm + wr + mt * 16 + rquad + i;
                    float val = acc[mt][nt][i] * (1.0f / 1024.0f);
                    if (col < 1024)
                        qkv[(size_t)row * 3072 + 1024 + col] = val + bk[col];
                    else if (col < 1040)
                        ab[(size_t)row * 32 + (col - 1024)] =
                            1.f / (1.f + expf(-val));
                    else if (col < 1056)
                        ab[(size_t)row * 32 + 16 + (col - 1040)] =
                            fmaxf(val, 0.f) + log1pf(expf(-fabsf(val)));
                }
            }
        }
    } else {
        const int n = blk - 272;
        const int bm = (n / 16) * 128;
        const int bn = (n % 16) * 128;
        const int wr = (wave >> 1) * 64;
        const int wc = (wave & 1) * 64;

        // A = hi section of Ae3, row stride KEXT
        const _Float16* gA0 = Ae3 + (size_t)(bm + wave * 32 + srow) * KEXT + scol;
        const _Float16* gA1 = gA0 + (size_t)16 * KEXT;
        const _Float16* gB0 = Bqv + (size_t)(bn + wave * 32 + srow) * 1024 + scol;
        const _Float16* gB1 = gB0 + (size_t)16 * 1024;
        _Float16* lA0_0 = &As[0][(wave * 32) * 32];
        _Float16* lA1_0 = &As[0][(wave * 32 + 16) * 32];
        _Float16* lB0_0 = &Bs[0][(wave * 32) * 32];
        _Float16* lB1_0 = &Bs[0][(wave * 32 + 16) * 32];
        _Float16* lA0_1 = &As[1][(wave * 32) * 32];
        _Float16* lA1_1 = &As[1][(wave * 32 + 16) * 32];
        _Float16* lB0_1 = &Bs[1][(wave * 32) * 32];
        _Float16* lB1_1 = &Bs[1][(wave * 32 + 16) * 32];

        f32x4 acc[4][4] = {};

        for (int k0 = 0; k0 < 1024; k0 += 64) {
            load_lds16(gA0 + k0,      lA0_0);
            load_lds16(gA1 + k0,      lA1_0);
            load_lds16(gB0 + k0,      lB0_0);
            load_lds16(gB1 + k0,      lB1_0);
            load_lds16(gA0 + k0 + 32, lA0_1);
            load_lds16(gA1 + k0 + 32, lA1_1);
            load_lds16(gB0 + k0 + 32, lB0_1);
            load_lds16(gB1 + k0 + 32, lB1_1);
            __syncthreads();

            #pragma unroll
            for (int s = 0; s < 2; ++s) {
                f16x8 a[4], b[4];
                #pragma unroll
                for (int mt = 0; mt < 4; ++mt)
                    a[mt] = *(const f16x8*)&As[s][(wr + mt * 16 + fm) * 32 + fq];
                #pragma unroll
                for (int nt = 0; nt < 4; ++nt)
                    b[nt] = *(const f16x8*)&Bs[s][(wc + nt * 16 + fm) * 32 + fq];
                #pragma unroll
                for (int mt = 0; mt < 4; ++mt)
                    #pragma unroll
                    for (int nt = 0; nt < 4; ++nt)
                        acc[mt][nt] = __builtin_amdgcn_mfma_f32_16x16x32_f16(
                            a[mt], b[nt], acc[mt][nt], 0, 0, 0);
            }
            __syncthreads();
        }

        #pragma unroll
        for (int mt = 0; mt < 4; ++mt) {
            #pragma unroll
            for (int nt = 0; nt < 4; ++nt) {
                const int col = bn + wc + nt * 16 + fm;
                #pragma unroll
                for (int i = 0; i < 4; ++i) {
                    const int row = bm + wr + mt * 16 + rquad + i;
                    float val = acc[mt][nt][i] * (1.0f / 1024.0f);
                    if (col < 1024)
                        qkv[(size_t)row * 3072 + col] = val + bq[col];
                    else
                        qkv[(size_t)row * 3072 + 1024 + col] = val + bv[col - 1024];
                }
            }
        }
    }
}

// ---------------------------------------------------------------------------
// Out-projection MFMA GEMM (unchanged): plain f16, K=1024, 128x64, BK=64.
// ---------------------------------------------------------------------------
__global__ __launch_bounds__(256) void mfma_gemm_out(
    const _Float16* __restrict__ Ae2, const _Float16* __restrict__ Be2,
    float* __restrict__ outp, const float* __restrict__ bo)
{
    __shared__ __align__(16) _Float16 As[2][128 * 32];
    __shared__ __align__(16) _Float16 Bs[2][64 * 32];

    const int tid = threadIdx.x;
    const int wave = tid >> 6;
    const int lane = tid & 63;
    const int bm = blockIdx.y * 128;
    const int bn = blockIdx.x * 64;
    const int wr = (wave >> 1) * 64;
    const int wc = (wave & 1) * 32;

    const int srow = lane >> 2;
    const int scol = (lane & 3) * 8;
    const _Float16* gA0 = Ae2 + (size_t)(bm + wave * 32 + srow) * 1024 + scol;
    const _Float16* gA1 = gA0 + (size_t)16 * 1024;
    const _Float16* gB0 = Be2 + (size_t)(bn + wave * 16 + srow) * 1024 + scol;
    _Float16* lA0_0 = &As[0][(wave * 32) * 32];
    _Float16* lA1_0 = &As[0][(wave * 32 + 16) * 32];
    _Float16* lB0_0 = &Bs[0][(wave * 16) * 32];
    _Float16* lA0_1 = &As[1][(wave * 32) * 32];
    _Float16* lA1_1 = &As[1][(wave * 32 + 16) * 32];
    _Float16* lB0_1 = &Bs[1][(wave * 16) * 32];

    const int fm = lane & 15;
    const int fq = (lane >> 4) * 8;

    f32x4 acc[4][2] = {};

    for (int k0 = 0; k0 < 1024; k0 += 64) {
        load_lds16(gA0 + k0,      lA0_0);
        load_lds16(gA1 + k0,      lA1_0);
        load_lds16(gB0 + k0,      lB0_0);
        load_lds16(gA0 + k0 + 32, lA0_1);
        load_lds16(gA1 + k0 + 32, lA1_1);
        load_lds16(gB0 + k0 + 32, lB0_1);
        __syncthreads();

        #pragma unroll
        for (int s = 0; s < 2; ++s) {
            f16x8 a[4], b[2];
            #pragma unroll
            for (int mt = 0; mt < 4; ++mt)
                a[mt] = *(const f16x8*)&As[s][(wr + mt * 16 + fm) * 32 + fq];
            #pragma unroll
            for (int nt = 0; nt < 2; ++nt)
                b[nt] = *(const f16x8*)&Bs[s][(wc + nt * 16 + fm) * 32 + fq];
            #pragma unroll
            for (int mt = 0; mt < 4; ++mt)
                #pragma unroll
                for (int nt = 0; nt < 2; ++nt)
                    acc[mt][nt] = __builtin_amdgcn_mfma_f32_16x16x32_f16(
                        a[mt], b[nt], acc[mt][nt], 0, 0, 0);
        }
        __syncthreads();
    }

    const int rquad = (lane >> 4) * 4;
    #pragma unroll
    for (int mt = 0; mt < 4; ++mt) {
        #pragma unroll
        for (int nt = 0; nt < 2; ++nt) {
            const int col = bn + wc + nt * 16 + fm;
            #pragma unroll
            for (int i = 0; i < 4; ++i) {
                const int row = bm + wr + mt * 16 + rquad + i;
                outp[(size_t)row * 1024 + col] = acc[mt][nt][i] * 64.f + bo[col];
            }
        }
    }
}

// ---------------------------------------------------------------------------
// DPP 16-lane reduction (xor1, xor2, row_ror:4, row_ror:8 -> all lanes hold sum)
// ---------------------------------------------------------------------------
template <int CTRL>
__device__ __forceinline__ float dpp_addf(float x) {
    int y = __builtin_amdgcn_update_dpp(0, __builtin_bit_cast(int, x),
                                        CTRL, 0xF, 0xF, true);
    return x + __builtin_bit_cast(float, y);
}
__device__ __forceinline__ float red16(float x) {
    x = dpp_addf<0xB1>(x);
    x = dpp_addf<0x4E>(x);
    x = dpp_addf<0x124>(x);
    x = dpp_addf<0x128>(x);
    return x;
}

// ---------------------------------------------------------------------------
// r15 recurrence support: pinned LDS->reg bursts via inline-asm volatile
// ds_read_b128 (the compiler re-sank source-level prefetches in r14 — VGPR
// count unchanged proved it; volatile asm cannot be sunk). One
// lgkmcnt(0)+sched_barrier(0) per burst (guide rule #18), then a 16-step
// pure-register run with ZERO memory instructions.
// ---------------------------------------------------------------------------
typedef __attribute__((address_space(3))) const float* lds_cfp;

__device__ __forceinline__ float4 ds_read_f4(lds_cfp p) {
    float4 d;
    asm volatile("ds_read_b128 %0, %1" : "=v"(d) : "v"(p));
    return d;
}

template <int I> struct RdKQ {
    static __device__ __forceinline__ void go(float4* k, float4* q,
                                              lds_cfp kb, lds_cfp qb) {
        k[I] = ds_read_f4(kb + I * 64);   // row stride 64 floats (256 B)
        q[I] = ds_read_f4(qb + I * 64);
        RdKQ<I + 1>::go(k, q, kb, qb);
    }
};
template <> struct RdKQ<16> {
    static __device__ __forceinline__ void go(float4*, float4*, lds_cfp, lds_cfp) {}
};

template <int I> struct RdVAB {
    static __device__ __forceinline__ void go(float4* v, float4* a, float4* b,
                                              lds_cfp vb, lds_cfp abb) {
        v[I] = ds_read_f4(vb + I * 4);          // 4 consecutive timesteps
        a[I] = ds_read_f4(abb + I * 4);         // a-row
        b[I] = ds_read_f4(abb + RCT + I * 4);   // b-row (+RCT floats)
        RdVAB<I + 1>::go(v, a, b, vb, abb);
    }
};
template <> struct RdVAB<4> {
    static __device__ __forceinline__ void go(float4*, float4*, float4*, lds_cfp, lds_cfp) {}
};

// r11's per-step math, VERBATIM, on registers only.
#define GDN_STEP(T, TBASE)                                              \
    {                                                                   \
        const float4 kc = kv[T];                                        \
        const float4 qc = qv[T];                                        \
        const float vc = vv[(T) >> 2][(T) & 3];                         \
        const float ac = av[(T) >> 2][(T) & 3];                         \
        const float bc = bv[(T) >> 2][(T) & 3];                         \
        float p0 = fmaf(S1, kc.y, S0 * kc.x);                           \
        float p1 = fmaf(S3, kc.w, S2 * kc.z);                           \
        float sk = red16(p0 + p1);                                      \
        const float cf = bc * fmaf(-ac, sk, vc);                        \
        S0 = fmaf(ac, S0, cf * kc.x);                                   \
        S1 = fmaf(ac, S1, cf * kc.y);                                   \
        S2 = fmaf(ac, S2, cf * kc.z);                                   \
        S3 = fmaf(ac, S3, cf * kc.w);                                   \
        float q0 = fmaf(S1, qc.y, S0 * qc.x);                           \
        float q1 = fmaf(S3, qc.w, S2 * qc.z);                           \
        float o = red16(q0 + q1);                                       \
        const int ph = (T) & 3;                                         \
        if (ph == 0) o0 = o;                                            \
        else if (ph == 1) o1 = o;                                       \
        else if (ph == 2) o2 = o;                                       \
        else if (el == 0)                                               \
            *(float4*)(op + (TBASE) + (T) - 3) = make_float4(o0, o1, o2, o); \
    }

// ---------------------------------------------------------------------------
// Gated delta recurrence — r15. r11 math verbatim; data movement restructured:
// per 16-step sub-chunk, burst 44 pinned ds_read_b128 into named registers
// (kv/qv 16 each, vv/av/bv 4 each), then run 16 steps with zero memory ops.
// v/ab LDS layout transposed ([row][t]) so bursts are float4 over time.
// 512 blocks x 64 threads; blk%32 = chain (XCD co-location), blk/32 = 4-row
// slice. Global->LDS staging (async, double-buffered) unchanged from r11.
// ---------------------------------------------------------------------------
__global__ __launch_bounds__(64) void gdn_recurrence(
    const float* __restrict__ qkv, const float* __restrict__ ab,
    float* __restrict__ att)
{
    __shared__ __align__(16) float ks[2][RCT][64];
    __shared__ __align__(16) float qs[2][RCT][64];
    __shared__ __align__(16) float vs_t[2][4][RCT];   // [buf][row][t]
    __shared__ __align__(16) float gab_t[2][2][RCT];  // [buf][a/b][t]

    const int blk = blockIdx.x;
    const int bh = blk & 31;          // chain (XCD co-location)
    const int s  = blk >> 5;          // row-slice 0..15
    const int b  = bh >> 4;
    const int h  = bh & 15;
    const int lane = threadIdx.x;
    const int rl = lane >> 4;         // local row 0..3
    const int el = lane & 15;         // e-slice
    const int e0 = el * 4;
    const int r0 = s * 4;

    const float* qb  = qkv + (size_t)b * LL * 3072 + h * 64;
    const float* kb  = qb + 1024;
    const float* vb  = qb + 2048 + r0;
    const float* abp = ab + (size_t)b * LL * 32 + h;
    float* op = att + ((size_t)(b * NH + h) * DD + r0 + rl) * LL;

    const int st = lane >> 4;          // t-within-4 for staging
    const int sd = (lane & 15) * 4;    // d offset

    float S0 = 0.f, S1 = 0.f, S2 = 0.f, S3 = 0.f;

    // ---- async-stage k/q chunk 0, reg-load v/ab chunk 0 (transposed) ----
    {
        const size_t ro = (size_t)st * 3072 + sd;
        #pragma unroll
        for (int m = 0; m < 8; ++m) {
            load_lds16(kb + ro + (size_t)m * 4 * 3072, &ks[0][m * 4][0]);
            load_lds16(qb + ro + (size_t)m * 4 * 3072, &qs[0][m * 4][0]);
        }
        float4 pv = make_float4(0.f,0.f,0.f,0.f);
        if (lane < RCT) pv = *(const float4*)(vb + (size_t)lane * 3072);
        float pab = (lane < 32) ? abp[(size_t)lane * 32]
                                : abp[(size_t)(lane - 32) * 32 + 16];
        if (lane < RCT) {
            vs_t[0][0][lane] = pv.x;
            vs_t[0][1][lane] = pv.y;
            vs_t[0][2][lane] = pv.z;
            vs_t[0][3][lane] = pv.w;
        }
        if (lane < 32) gab_t[0][0][lane] = pab;
        else           gab_t[0][1][lane - 32] = pab;
    }
    __syncthreads();

    const int NCHUNK = LL / RCT;
    for (int c = 0; c < NCHUNK; ++c) {
        const int cur = c & 1, nxt = cur ^ 1;
        const bool more = (c + 1 < NCHUNK);

        // issue async staging for chunk c+1; tiny reg prefetch for v/ab
        float4 pv = make_float4(0.f,0.f,0.f,0.f);
        float pab = 0.f;
        if (more) {
            const size_t t0 = (size_t)(c + 1) * RCT;
            const size_t ro = (t0 + st) * 3072 + sd;
            #pragma unroll
            for (int m = 0; m < 8; ++m) {
                load_lds16(kb + ro + (size_t)m * 4 * 3072, &ks[nxt][m * 4][0]);
                load_lds16(qb + ro + (size_t)m * 4 * 3072, &qs[nxt][m * 4][0]);
            }
            if (lane < RCT) pv = *(const float4*)(vb + (t0 + lane) * 3072);
            pab = (lane < 32) ? abp[(t0 + lane) * 32]
                              : abp[(t0 + lane - 32) * 32 + 16];
        }

        float4 kv[16], qv[16], vv[4], av[4], bv[4];
        float o0 = 0.f, o1 = 0.f, o2 = 0.f;

        // ---- sub-chunk 0: pinned burst, then 16 pure-register steps ----
        RdKQ<0>::go(kv, qv, (lds_cfp)&ks[cur][0][e0], (lds_cfp)&qs[cur][0][e0]);
        RdVAB<0>::go(vv, av, bv, (lds_cfp)&vs_t[cur][rl][0],
                     (lds_cfp)&gab_t[cur][0][0]);
        asm volatile("s_waitcnt lgkmcnt(0)" ::: "memory");
        __builtin_amdgcn_sched_barrier(0);
        #pragma unroll
        for (int t = 0; t < 16; ++t) GDN_STEP(t, c * RCT);

        // ---- sub-chunk 1 ----
        RdKQ<0>::go(kv, qv, (lds_cfp)&ks[cur][16][e0], (lds_cfp)&qs[cur][16][e0]);
        RdVAB<0>::go(vv, av, bv, (lds_cfp)&vs_t[cur][rl][16],
                     (lds_cfp)&gab_t[cur][0][16]);
        asm volatile("s_waitcnt lgkmcnt(0)" ::: "memory");
        __builtin_amdgcn_sched_barrier(0);
        #pragma unroll
        for (int t = 0; t < 16; ++t) GDN_STEP(t, c * RCT + 16);

        // commit v/ab prefetch into next buffer (transposed), then publish
        if (more) {
            if (lane < RCT) {
                vs_t[nxt][0][lane] = pv.x;
                vs_t[nxt][1][lane] = pv.y;
                vs_t[nxt][2][lane] = pv.z;
                vs_t[nxt][3][lane] = pv.w;
            }
            if (lane < 32) gab_t[nxt][0][lane] = pab;
            else           gab_t[nxt][1][lane - 32] = pab;
        }
        __syncthreads();
    }
}

// ---------------------------------------------------------------------------
// Fused: residual depthwise causal conv (bug-compat reshaped view) +
// transpose back + f16 convert (hi only) for the out-projection A matrix.
// ---------------------------------------------------------------------------
__global__ __launch_bounds__(256) void conv_convert(
    const float* __restrict__ att, const float* __restrict__ Wconv,
    _Float16* __restrict__ Ae2)
{
    __shared__ float yt[112][68];
    const int lb = blockIdx.x;
    const int h  = blockIdx.y;
    const int b  = blockIdx.z;
    const int tid = threadIdx.x;

    {
        const int d = tid >> 2;
        const int part = tid & 3;
        const float* src  = att + ((size_t)(b * NH + h) * DD + d) * LL;
        const float* srcm = src - (size_t)DD * LL;
        #pragma unroll
        for (int m = 0; m < 7; ++m) {
            const int off = (part * 7 + m) * 4;
            const int lg = lb * 64 - 48 + off;
            float4 v;
            if (lg >= 0)      v = *(const float4*)(src + lg);
            else if (h > 0)   v = *(const float4*)(srcm + lg + 1024);
            else              v = make_float4(0.f, 0.f, 0.f, 0.f);
            yt[off + 0][d] = v.x; yt[off + 1][d] = v.y;
            yt[off + 2][d] = v.z; yt[off + 3][d] = v.w;
        }
    }
    __syncthreads();

    float4 w[4];
    #pragma unroll
    for (int k = 0; k < 4; ++k)
        w[k] = ((const float4*)Wconv)[tid * 4 + k];

    const int d0 = (tid & 15) * 4;
    const int lq = tid >> 4;
    const float sc = 1.f / 4096.f;

    #pragma unroll
    for (int rr = 0; rr < 4; ++rr) {
        const int ll = rr * 16 + lq;
        float y0[4], y1[4], y2[4], y3[4];
        *(float4*)y0 = *(const float4*)&yt[ll +  0][d0];
        *(float4*)y1 = *(const float4*)&yt[ll + 16][d0];
        *(float4*)y2 = *(const float4*)&yt[ll + 32][d0];
        *(float4*)y3 = *(const float4*)&yt[ll + 48][d0];
        f16x4 hi;
        #pragma unroll
        for (int k = 0; k < 4; ++k) {
            float acc = y3[k];
            acc = fmaf(w[k].x, y0[k], acc);
            acc = fmaf(w[k].y, y1[k], acc);
            acc = fmaf(w[k].z, y2[k], acc);
            acc = fmaf(w[k].w, y3[k], acc);
            hi[k] = (_Float16)(acc * sc);
        }
        const size_t row = (size_t)b * 1024 + h * 64 + lb * 4 + rr;
        *(f16x4*)(Ae2 + row * 1024 + tid * 4) = hi;
    }
}

// ---------------------------------------------------------------------------
extern "C" void kernel_launch(void* const* d_in, const int* in_sizes, int n_in,
                              void* d_out, int out_size, void* d_ws, size_t ws_size,
                              hipStream_t stream)
{
    const float* hs    = (const float*)d_in[0];
    const float* Wq    = (const float*)d_in[1];
    const float* bq    = (const float*)d_in[2];
    const float* Wk    = (const float*)d_in[3];
    const float* bk    = (const float*)d_in[4];
    const float* Wv    = (const float*)d_in[5];
    const float* bv    = (const float*)d_in[6];
    const float* Wa    = (const float*)d_in[7];
    const float* Wb    = (const float*)d_in[8];
    const float* Wconv = (const float*)d_in[9];
    const float* Wo    = (const float*)d_in[10];
    const float* bo    = (const float*)d_in[11];
    float* out = (float*)d_out;

    // workspace layout (~63 MB)
    char* w = (char*)d_ws;
    float* qkv = (float*)w;        w += (size_t)MM * 3072 * 4;      // 25.2 MB
    float* att = (float*)w;        w += (size_t)MM * 1024 * 4;      //  8.4 MB ([B][NH][D][L])
    float* ab  = (float*)w;        w += (size_t)MM * 32 * 4;        //  0.26 MB
    _Float16* Ae3 = (_Float16*)w;  w += (size_t)MM * KEXT * 2;      // 12.6 MB
    _Float16* Bk  = (_Float16*)w;  w += (size_t)NBK * KEXT * 2;     //  6.7 MB
    _Float16* Bqv = (_Float16*)w;  w += (size_t)2048 * 1024 * 2;    //  4.2 MB
    _Float16* Ae2 = (_Float16*)w;  w += (size_t)MM * 1024 * 2;      //  4.2 MB
    _Float16* Be2 = (_Float16*)w;  w += (size_t)1024 * 1024 * 2;    //  2.1 MB

    // 1) conversions (hs->Ae3, Wk/Wa/Wb->Bk, Wq|Wv->Bqv, Wo->Be2)
    hipLaunchKernelGGL(convert_front, dim3(6208), dim3(256), 0, stream,
                       hs, Wq, Wk, Wv, Wa, Wb, Wo, Ae3, Bk, Bqv, Be2);

    // 2) merged projection GEMM (k+ab 272 blocks | q+v 256 blocks)
    hipLaunchKernelGGL(mfma_gemm_proj, dim3(528), dim3(256), 0, stream,
                       Ae3, Bk, Bqv, qkv, ab, bq, bk, bv);

    // 3) gated delta recurrence (r15: pinned register bursts, zero-mem inner loop)
    hipLaunchKernelGGL(gdn_recurrence, dim3(512), dim3(64), 0, stream, qkv, ab, att);

    // 4) fused conv + transpose + f16 convert (hi only, writes Ae2)
    hipLaunchKernelGGL(conv_convert, dim3(16, 16, BB), dim3(256), 0, stream,
                       att, Wconv, Ae2);

    // 5) out-projection (plain f16, K=1024, 128x64 tiles -> 256 blocks)
    hipLaunchKernelGGL(mfma_gemm_out, dim3(1024 / 64, MM / 128), dim3(256), 0, stream,
                       Ae2, Be2, out, bo);
}

// Round 4
// 281.343 us; speedup vs baseline: 1.0466x; 1.0466x over previous
//
#include <hip/hip_runtime.h>
#include <math.h>

// Problem constants
#define BB 2
#define LL 1024
#define HH 1024
#define NH 16
#define DD 64
#define HD (NH * DD)   // 1024
#define MM (BB * LL)   // 2048
#define RCT 32         // recurrence chunk length staged in LDS
#define KEXT 3072      // extended K for f16 hi/lo split GEMM (3 x 1024)
#define NBK 1088       // k-GEMM B rows: 1024 k + 16 alpha + 16 beta + 32 pad

typedef _Float16 f16x8 __attribute__((ext_vector_type(8)));
typedef _Float16 f16x4 __attribute__((ext_vector_type(4)));
typedef float f32x4 __attribute__((ext_vector_type(4)));

// ---------------------------------------------------------------------------
// async global->LDS, 16B per lane; LDS dest = wave-uniform base + lane*16
// ---------------------------------------------------------------------------
__device__ __forceinline__ void load_lds16(const void* g, void* l) {
    __builtin_amdgcn_global_load_lds(
        (const __attribute__((address_space(1))) void*)g,
        (__attribute__((address_space(3))) void*)l, 16, 0, 0);
}

// ---------------------------------------------------------------------------
// Conversions. Only k/alpha/beta compound through the recurrence -> 3-split
// f16 (K=3072); q (readout) and v (additive) are plain f16 and read the hi
// section of Ae3 directly (row stride KEXT) — no separate Ah copy.
//   blocks [0,2048):        hs -> Ae3 (x16, [hi|lo|hi])
//   blocks [2048,3136):     Wk/Wa/Wb -> Bk (x64, [hi|hi|lo]), rows>=1056 zero
//   blocks [3136,5184):     Wq|Wv -> Bqv (x64, hi only)
//   blocks [5184,6208):     Wo -> Be2 (x64, hi only)
// ---------------------------------------------------------------------------
__global__ __launch_bounds__(256) void convert_front(
    const float* __restrict__ hs,
    const float* __restrict__ Wq, const float* __restrict__ Wk,
    const float* __restrict__ Wv, const float* __restrict__ Wa,
    const float* __restrict__ Wb, const float* __restrict__ Wo,
    _Float16* __restrict__ Ae3,
    _Float16* __restrict__ Bk, _Float16* __restrict__ Bqv,
    _Float16* __restrict__ Be2)
{
    const int blk = blockIdx.x;
    const int t = threadIdx.x;

    if (blk < 2048) {             // hs -> Ae3 (3-split)
        float4 x = *(const float4*)(hs + (size_t)blk * 1024 + t * 4);
        x.x *= 16.f; x.y *= 16.f; x.z *= 16.f; x.w *= 16.f;
        f16x4 h, l;
        h[0] = (_Float16)x.x; l[0] = (_Float16)(x.x - (float)h[0]);
        h[1] = (_Float16)x.y; l[1] = (_Float16)(x.y - (float)h[1]);
        h[2] = (_Float16)x.z; l[2] = (_Float16)(x.z - (float)h[2]);
        h[3] = (_Float16)x.w; l[3] = (_Float16)(x.w - (float)h[3]);
        _Float16* base = Ae3 + (size_t)blk * KEXT + t * 4;
        *(f16x4*)(base)        = h;
        *(f16x4*)(base + 1024) = l;
        *(f16x4*)(base + 2048) = h;
        return;
    }
    if (blk < 3136) {             // Wk/Wa/Wb -> Bk (3-split, B-order)
        const int n = blk - 2048;
        const float* src = nullptr;
        if (n < 1024)      src = Wk + (size_t)n * 1024;
        else if (n < 1040) src = Wa + (size_t)(n - 1024) * 1024;
        else if (n < 1056) src = Wb + (size_t)(n - 1040) * 1024;
        float4 x = src ? *(const float4*)(src + t * 4)
                       : make_float4(0.f, 0.f, 0.f, 0.f);
        x.x *= 64.f; x.y *= 64.f; x.z *= 64.f; x.w *= 64.f;
        f16x4 h, l;
        h[0] = (_Float16)x.x; l[0] = (_Float16)(x.x - (float)h[0]);
        h[1] = (_Float16)x.y; l[1] = (_Float16)(x.y - (float)h[1]);
        h[2] = (_Float16)x.z; l[2] = (_Float16)(x.z - (float)h[2]);
        h[3] = (_Float16)x.w; l[3] = (_Float16)(x.w - (float)h[3]);
        _Float16* base = Bk + (size_t)n * KEXT + t * 4;
        *(f16x4*)(base)        = h;
        *(f16x4*)(base + 1024) = h;
        *(f16x4*)(base + 2048) = l;
        return;
    }
    if (blk < 5184) {             // Wq|Wv -> Bqv (hi only)
        const int n = blk - 3136;
        const float* src = (n < 1024) ? Wq + (size_t)n * 1024
                                      : Wv + (size_t)(n - 1024) * 1024;
        float4 x = *(const float4*)(src + t * 4);
        f16x4 h;
        h[0] = (_Float16)(x.x * 64.f);
        h[1] = (_Float16)(x.y * 64.f);
        h[2] = (_Float16)(x.z * 64.f);
        h[3] = (_Float16)(x.w * 64.f);
        *(f16x4*)(Bqv + (size_t)n * 1024 + t * 4) = h;
        return;
    }
    {                             // Wo -> Be2 (hi only)
        const int n = blk - 5184;
        float4 x = *(const float4*)(Wo + (size_t)n * 1024 + t * 4);
        f16x4 h;
        h[0] = (_Float16)(x.x * 64.f);
        h[1] = (_Float16)(x.y * 64.f);
        h[2] = (_Float16)(x.z * 64.f);
        h[3] = (_Float16)(x.w * 64.f);
        *(f16x4*)(Be2 + (size_t)n * 1024 + t * 4) = h;
    }
}

// ---------------------------------------------------------------------------
// MERGED projection GEMM: 528 blocks.
//   blk <  272: k+ab part — Ae3 @ Bk^T, K=3072, 128x64 tile (17 N-tiles).
//   blk >= 272: q|v part  — Ae3-hi @ Bqv^T, K=1024, 128x128 tile (A row
//               stride KEXT, hi section).
// ---------------------------------------------------------------------------
__global__ __launch_bounds__(256) void mfma_gemm_proj(
    const _Float16* __restrict__ Ae3, const _Float16* __restrict__ Bk,
    const _Float16* __restrict__ Bqv,
    float* __restrict__ qkv, float* __restrict__ ab,
    const float* __restrict__ bq, const float* __restrict__ bk,
    const float* __restrict__ bv)
{
    __shared__ __align__(16) _Float16 As[2][128 * 32];
    __shared__ __align__(16) _Float16 Bs[2][128 * 32];

    const int blk = blockIdx.x;
    const int tid = threadIdx.x;
    const int wave = tid >> 6;
    const int lane = tid & 63;
    const int srow = lane >> 2;
    const int scol = (lane & 3) * 8;
    const int fm = lane & 15;
    const int fq = (lane >> 4) * 8;
    const int rquad = (lane >> 4) * 4;

    if (blk < 272) {
        const int bm = (blk / 17) * 128;
        const int bn = (blk % 17) * 64;
        const int wr = (wave >> 1) * 64;
        const int wc = (wave & 1) * 32;

        const _Float16* gA0 = Ae3 + (size_t)(bm + wave * 32 + srow) * KEXT + scol;
        const _Float16* gA1 = gA0 + (size_t)16 * KEXT;
        const _Float16* gB0 = Bk + (size_t)(bn + wave * 16 + srow) * KEXT + scol;
        _Float16* lA0_0 = &As[0][(wave * 32) * 32];
        _Float16* lA1_0 = &As[0][(wave * 32 + 16) * 32];
        _Float16* lB0_0 = &Bs[0][(wave * 16) * 32];
        _Float16* lA0_1 = &As[1][(wave * 32) * 32];
        _Float16* lA1_1 = &As[1][(wave * 32 + 16) * 32];
        _Float16* lB0_1 = &Bs[1][(wave * 16) * 32];

        f32x4 acc[4][2] = {};

        for (int k0 = 0; k0 < KEXT; k0 += 64) {
            load_lds16(gA0 + k0,      lA0_0);
            load_lds16(gA1 + k0,      lA1_0);
            load_lds16(gB0 + k0,      lB0_0);
            load_lds16(gA0 + k0 + 32, lA0_1);
            load_lds16(gA1 + k0 + 32, lA1_1);
            load_lds16(gB0 + k0 + 32, lB0_1);
            __syncthreads();

            #pragma unroll
            for (int s = 0; s < 2; ++s) {
                f16x8 a[4], b[2];
                #pragma unroll
                for (int mt = 0; mt < 4; ++mt)
                    a[mt] = *(const f16x8*)&As[s][(wr + mt * 16 + fm) * 32 + fq];
                #pragma unroll
                for (int nt = 0; nt < 2; ++nt)
                    b[nt] = *(const f16x8*)&Bs[s][(wc + nt * 16 + fm) * 32 + fq];
                #pragma unroll
                for (int mt = 0; mt < 4; ++mt)
                    #pragma unroll
                    for (int nt = 0; nt < 2; ++nt)
                        acc[mt][nt] = __builtin_amdgcn_mfma_f32_16x16x32_f16(
                            a[mt], b[nt], acc[mt][nt], 0, 0, 0);
            }
            __syncthreads();
        }

        #pragma unroll
        for (int mt = 0; mt < 4; ++mt) {
            #pragma unroll
            for (int nt = 0; nt < 2; ++nt) {
                const int col = bn + wc + nt * 16 + fm;
                #pragma unroll
                for (int i = 0; i < 4; ++i) {
                    const int row = bm + wr + mt * 16 + rquad + i;
                    float val = acc[mt][nt][i] * (1.0f / 1024.0f);
                    if (col < 1024)
                        qkv[(size_t)row * 3072 + 1024 + col] = val + bk[col];
                    else if (col < 1040)
                        ab[(size_t)row * 32 + (col - 1024)] =
                            1.f / (1.f + expf(-val));
                    else if (col < 1056)
                        ab[(size_t)row * 32 + 16 + (col - 1040)] =
                            fmaxf(val, 0.f) + log1pf(expf(-fabsf(val)));
                }
            }
        }
    } else {
        const int n = blk - 272;
        const int bm = (n / 16) * 128;
        const int bn = (n % 16) * 128;
        const int wr = (wave >> 1) * 64;
        const int wc = (wave & 1) * 64;

        // A = hi section of Ae3, row stride KEXT
        const _Float16* gA0 = Ae3 + (size_t)(bm + wave * 32 + srow) * KEXT + scol;
        const _Float16* gA1 = gA0 + (size_t)16 * KEXT;
        const _Float16* gB0 = Bqv + (size_t)(bn + wave * 32 + srow) * 1024 + scol;
        const _Float16* gB1 = gB0 + (size_t)16 * 1024;
        _Float16* lA0_0 = &As[0][(wave * 32) * 32];
        _Float16* lA1_0 = &As[0][(wave * 32 + 16) * 32];
        _Float16* lB0_0 = &Bs[0][(wave * 32) * 32];
        _Float16* lB1_0 = &Bs[0][(wave * 32 + 16) * 32];
        _Float16* lA0_1 = &As[1][(wave * 32) * 32];
        _Float16* lA1_1 = &As[1][(wave * 32 + 16) * 32];
        _Float16* lB0_1 = &Bs[1][(wave * 32) * 32];
        _Float16* lB1_1 = &Bs[1][(wave * 32 + 16) * 32];

        f32x4 acc[4][4] = {};

        for (int k0 = 0; k0 < 1024; k0 += 64) {
            load_lds16(gA0 + k0,      lA0_0);
            load_lds16(gA1 + k0,      lA1_0);
            load_lds16(gB0 + k0,      lB0_0);
            load_lds16(gB1 + k0,      lB1_0);
            load_lds16(gA0 + k0 + 32, lA0_1);
            load_lds16(gA1 + k0 + 32, lA1_1);
            load_lds16(gB0 + k0 + 32, lB0_1);
            load_lds16(gB1 + k0 + 32, lB1_1);
            __syncthreads();

            #pragma unroll
            for (int s = 0; s < 2; ++s) {
                f16x8 a[4], b[4];
                #pragma unroll
                for (int mt = 0; mt < 4; ++mt)
                    a[mt] = *(const f16x8*)&As[s][(wr + mt * 16 + fm) * 32 + fq];
                #pragma unroll
                for (int nt = 0; nt < 4; ++nt)
                    b[nt] = *(const f16x8*)&Bs[s][(wc + nt * 16 + fm) * 32 + fq];
                #pragma unroll
                for (int mt = 0; mt < 4; ++mt)
                    #pragma unroll
                    for (int nt = 0; nt < 4; ++nt)
                        acc[mt][nt] = __builtin_amdgcn_mfma_f32_16x16x32_f16(
                            a[mt], b[nt], acc[mt][nt], 0, 0, 0);
            }
            __syncthreads();
        }

        #pragma unroll
        for (int mt = 0; mt < 4; ++mt) {
            #pragma unroll
            for (int nt = 0; nt < 4; ++nt) {
                const int col = bn + wc + nt * 16 + fm;
                #pragma unroll
                for (int i = 0; i < 4; ++i) {
                    const int row = bm + wr + mt * 16 + rquad + i;
                    float val = acc[mt][nt][i] * (1.0f / 1024.0f);
                    if (col < 1024)
                        qkv[(size_t)row * 3072 + col] = val + bq[col];
                    else
                        qkv[(size_t)row * 3072 + 1024 + col] = val + bv[col - 1024];
                }
            }
        }
    }
}

// ---------------------------------------------------------------------------
// Out-projection MFMA GEMM (unchanged): plain f16, K=1024, 128x64, BK=64.
// ---------------------------------------------------------------------------
__global__ __launch_bounds__(256) void mfma_gemm_out(
    const _Float16* __restrict__ Ae2, const _Float16* __restrict__ Be2,
    float* __restrict__ outp, const float* __restrict__ bo)
{
    __shared__ __align__(16) _Float16 As[2][128 * 32];
    __shared__ __align__(16) _Float16 Bs[2][64 * 32];

    const int tid = threadIdx.x;
    const int wave = tid >> 6;
    const int lane = tid & 63;
    const int bm = blockIdx.y * 128;
    const int bn = blockIdx.x * 64;
    const int wr = (wave >> 1) * 64;
    const int wc = (wave & 1) * 32;

    const int srow = lane >> 2;
    const int scol = (lane & 3) * 8;
    const _Float16* gA0 = Ae2 + (size_t)(bm + wave * 32 + srow) * 1024 + scol;
    const _Float16* gA1 = gA0 + (size_t)16 * 1024;
    const _Float16* gB0 = Be2 + (size_t)(bn + wave * 16 + srow) * 1024 + scol;
    _Float16* lA0_0 = &As[0][(wave * 32) * 32];
    _Float16* lA1_0 = &As[0][(wave * 32 + 16) * 32];
    _Float16* lB0_0 = &Bs[0][(wave * 16) * 32];
    _Float16* lA0_1 = &As[1][(wave * 32) * 32];
    _Float16* lA1_1 = &As[1][(wave * 32 + 16) * 32];
    _Float16* lB0_1 = &Bs[1][(wave * 16) * 32];

    const int fm = lane & 15;
    const int fq = (lane >> 4) * 8;

    f32x4 acc[4][2] = {};

    for (int k0 = 0; k0 < 1024; k0 += 64) {
        load_lds16(gA0 + k0,      lA0_0);
        load_lds16(gA1 + k0,      lA1_0);
        load_lds16(gB0 + k0,      lB0_0);
        load_lds16(gA0 + k0 + 32, lA0_1);
        load_lds16(gA1 + k0 + 32, lA1_1);
        load_lds16(gB0 + k0 + 32, lB0_1);
        __syncthreads();

        #pragma unroll
        for (int s = 0; s < 2; ++s) {
            f16x8 a[4], b[2];
            #pragma unroll
            for (int mt = 0; mt < 4; ++mt)
                a[mt] = *(const f16x8*)&As[s][(wr + mt * 16 + fm) * 32 + fq];
            #pragma unroll
            for (int nt = 0; nt < 2; ++nt)
                b[nt] = *(const f16x8*)&Bs[s][(wc + nt * 16 + fm) * 32 + fq];
            #pragma unroll
            for (int mt = 0; mt < 4; ++mt)
                #pragma unroll
                for (int nt = 0; nt < 2; ++nt)
                    acc[mt][nt] = __builtin_amdgcn_mfma_f32_16x16x32_f16(
                        a[mt], b[nt], acc[mt][nt], 0, 0, 0);
        }
        __syncthreads();
    }

    const int rquad = (lane >> 4) * 4;
    #pragma unroll
    for (int mt = 0; mt < 4; ++mt) {
        #pragma unroll
        for (int nt = 0; nt < 2; ++nt) {
            const int col = bn + wc + nt * 16 + fm;
            #pragma unroll
            for (int i = 0; i < 4; ++i) {
                const int row = bm + wr + mt * 16 + rquad + i;
                outp[(size_t)row * 1024 + col] = acc[mt][nt][i] * 64.f + bo[col];
            }
        }
    }
}

// ---------------------------------------------------------------------------
// DPP 16-lane reduction (xor1, xor2, row_ror:4, row_ror:8 -> all lanes hold sum)
// ---------------------------------------------------------------------------
template <int CTRL>
__device__ __forceinline__ float dpp_addf(float x) {
    int y = __builtin_amdgcn_update_dpp(0, __builtin_bit_cast(int, x),
                                        CTRL, 0xF, 0xF, true);
    return x + __builtin_bit_cast(float, y);
}
__device__ __forceinline__ float red16(float x) {
    x = dpp_addf<0xB1>(x);
    x = dpp_addf<0x4E>(x);
    x = dpp_addf<0x124>(x);
    x = dpp_addf<0x128>(x);
    return x;
}

// ---------------------------------------------------------------------------
// r15/r16 recurrence support: pinned LDS->reg bursts via inline-asm volatile
// ds_read_b128 (cannot be sunk/resched by the compiler). One
// lgkmcnt(0)+sched_barrier(0) per burst (guide rule #18), then a 16-step
// pure-register run with ZERO memory instructions.
// ---------------------------------------------------------------------------
typedef __attribute__((address_space(3))) const float* lds_cfp;

__device__ __forceinline__ float4 ds_read_f4(lds_cfp p) {
    float4 d;
    asm volatile("ds_read_b128 %0, %1" : "=v"(d) : "v"(p));
    return d;
}

template <int I> struct RdKQ {
    static __device__ __forceinline__ void go(float4* k, float4* q,
                                              lds_cfp kb, lds_cfp qb) {
        k[I] = ds_read_f4(kb + I * 64);   // row stride 64 floats (256 B)
        q[I] = ds_read_f4(qb + I * 64);
        RdKQ<I + 1>::go(k, q, kb, qb);
    }
};
template <> struct RdKQ<16> {
    static __device__ __forceinline__ void go(float4*, float4*, lds_cfp, lds_cfp) {}
};

template <int I> struct RdVAB {
    static __device__ __forceinline__ void go(float4* v, float4* a, float4* b,
                                              lds_cfp vb, lds_cfp abb) {
        v[I] = ds_read_f4(vb + I * 4);          // 4 consecutive timesteps
        a[I] = ds_read_f4(abb + I * 4);         // a-row
        b[I] = ds_read_f4(abb + RCT + I * 4);   // b-row (+RCT floats)
        RdVAB<I + 1>::go(v, a, b, vb, abb);
    }
};
template <> struct RdVAB<4> {
    static __device__ __forceinline__ void go(float4*, float4*, float4*, lds_cfp, lds_cfp) {}
};

// r16: r11's per-step math, but the step ends at the IN-LANE partial
// qp[T] = q0+q1. The 16 cross-lane output reductions (4 DPP levels each)
// run AFTER the 16-step run as interleaved independent chains — same
// instructions, moved off the carried dependency walk. (r15 post-mortem:
// wall time == serial chain latency exactly; output red16 was the largest
// algebraically-removable segment of that walk.)
#define GDN_STEP(T)                                                     \
    {                                                                   \
        const float4 kc = kv[T];                                        \
        const float4 qc = qv[T];                                        \
        const float vc = vv[(T) >> 2][(T) & 3];                         \
        const float ac = av[(T) >> 2][(T) & 3];                         \
        const float bc = bvr[(T) >> 2][(T) & 3];                        \
        float p0 = fmaf(S1, kc.y, S0 * kc.x);                           \
        float p1 = fmaf(S3, kc.w, S2 * kc.z);                           \
        float sk = red16(p0 + p1);                                      \
        const float cf = bc * fmaf(-ac, sk, vc);                        \
        S0 = fmaf(ac, S0, cf * kc.x);                                   \
        S1 = fmaf(ac, S1, cf * kc.y);                                   \
        S2 = fmaf(ac, S2, cf * kc.z);                                   \
        S3 = fmaf(ac, S3, cf * kc.w);                                   \
        float q0 = fmaf(S1, qc.y, S0 * qc.x);                           \
        float q1 = fmaf(S3, qc.w, S2 * qc.z);                           \
        qp[T] = q0 + q1;                                                \
    }

// 16 deferred cross-lane reductions + 4 vectorized stores.
#define GDN_FLUSH(TBASE)                                                \
    {                                                                   \
        _Pragma("unroll")                                               \
        for (int i = 0; i < 16; ++i) qp[i] = dpp_addf<0xB1>(qp[i]);     \
        _Pragma("unroll")                                               \
        for (int i = 0; i < 16; ++i) qp[i] = dpp_addf<0x4E>(qp[i]);     \
        _Pragma("unroll")                                               \
        for (int i = 0; i < 16; ++i) qp[i] = dpp_addf<0x124>(qp[i]);    \
        _Pragma("unroll")                                               \
        for (int i = 0; i < 16; ++i) qp[i] = dpp_addf<0x128>(qp[i]);    \
        if (el == 0) {                                                  \
            *(float4*)(op + (TBASE) + 0)  = make_float4(qp[0],  qp[1],  qp[2],  qp[3]);  \
            *(float4*)(op + (TBASE) + 4)  = make_float4(qp[4],  qp[5],  qp[6],  qp[7]);  \
            *(float4*)(op + (TBASE) + 8)  = make_float4(qp[8],  qp[9],  qp[10], qp[11]); \
            *(float4*)(op + (TBASE) + 12) = make_float4(qp[12], qp[13], qp[14], qp[15]); \
        }                                                               \
    }

// ---------------------------------------------------------------------------
// Gated delta recurrence — r16. r15 structure verbatim (pinned bursts,
// zero-mem 16-step runs); single variable changed: output red16 deferred
// out of the carried walk (GDN_STEP ends at in-lane partial; GDN_FLUSH does
// 16 interleaved DPP chains after the run). Zero instruction-count delta.
// 512 blocks x 64 threads; blk%32 = chain (XCD co-location), blk/32 = 4-row
// slice. Global->LDS staging (async, double-buffered) unchanged from r11.
// ---------------------------------------------------------------------------
__global__ __launch_bounds__(64) void gdn_recurrence(
    const float* __restrict__ qkv, const float* __restrict__ ab,
    float* __restrict__ att)
{
    __shared__ __align__(16) float ks[2][RCT][64];
    __shared__ __align__(16) float qs[2][RCT][64];
    __shared__ __align__(16) float vs_t[2][4][RCT];   // [buf][row][t]
    __shared__ __align__(16) float gab_t[2][2][RCT];  // [buf][a/b][t]

    const int blk = blockIdx.x;
    const int bh = blk & 31;          // chain (XCD co-location)
    const int s  = blk >> 5;          // row-slice 0..15
    const int b  = bh >> 4;
    const int h  = bh & 15;
    const int lane = threadIdx.x;
    const int rl = lane >> 4;         // local row 0..3
    const int el = lane & 15;         // e-slice
    const int e0 = el * 4;
    const int r0 = s * 4;

    const float* qb  = qkv + (size_t)b * LL * 3072 + h * 64;
    const float* kb  = qb + 1024;
    const float* vb  = qb + 2048 + r0;
    const float* abp = ab + (size_t)b * LL * 32 + h;
    float* op = att + ((size_t)(b * NH + h) * DD + r0 + rl) * LL;

    const int st = lane >> 4;          // t-within-4 for staging
    const int sd = (lane & 15) * 4;    // d offset

    float S0 = 0.f, S1 = 0.f, S2 = 0.f, S3 = 0.f;

    // ---- async-stage k/q chunk 0, reg-load v/ab chunk 0 (transposed) ----
    {
        const size_t ro = (size_t)st * 3072 + sd;
        #pragma unroll
        for (int m = 0; m < 8; ++m) {
            load_lds16(kb + ro + (size_t)m * 4 * 3072, &ks[0][m * 4][0]);
            load_lds16(qb + ro + (size_t)m * 4 * 3072, &qs[0][m * 4][0]);
        }
        float4 pv = make_float4(0.f,0.f,0.f,0.f);
        if (lane < RCT) pv = *(const float4*)(vb + (size_t)lane * 3072);
        float pab = (lane < 32) ? abp[(size_t)lane * 32]
                                : abp[(size_t)(lane - 32) * 32 + 16];
        if (lane < RCT) {
            vs_t[0][0][lane] = pv.x;
            vs_t[0][1][lane] = pv.y;
            vs_t[0][2][lane] = pv.z;
            vs_t[0][3][lane] = pv.w;
        }
        if (lane < 32) gab_t[0][0][lane] = pab;
        else           gab_t[0][1][lane - 32] = pab;
    }
    __syncthreads();

    const int NCHUNK = LL / RCT;
    for (int c = 0; c < NCHUNK; ++c) {
        const int cur = c & 1, nxt = cur ^ 1;
        const bool more = (c + 1 < NCHUNK);

        // issue async staging for chunk c+1; tiny reg prefetch for v/ab
        float4 pv = make_float4(0.f,0.f,0.f,0.f);
        float pab = 0.f;
        if (more) {
            const size_t t0 = (size_t)(c + 1) * RCT;
            const size_t ro = (t0 + st) * 3072 + sd;
            #pragma unroll
            for (int m = 0; m < 8; ++m) {
                load_lds16(kb + ro + (size_t)m * 4 * 3072, &ks[nxt][m * 4][0]);
                load_lds16(qb + ro + (size_t)m * 4 * 3072, &qs[nxt][m * 4][0]);
            }
            if (lane < RCT) pv = *(const float4*)(vb + (t0 + lane) * 3072);
            pab = (lane < 32) ? abp[(t0 + lane) * 32]
                              : abp[(t0 + lane - 32) * 32 + 16];
        }

        float4 kv[16], qv[16], vv[4], av[4], bvr[4];
        float qp[16];

        // ---- sub-chunk 0: pinned burst, 16 pure-register steps, flush ----
        RdKQ<0>::go(kv, qv, (lds_cfp)&ks[cur][0][e0], (lds_cfp)&qs[cur][0][e0]);
        RdVAB<0>::go(vv, av, bvr, (lds_cfp)&vs_t[cur][rl][0],
                     (lds_cfp)&gab_t[cur][0][0]);
        asm volatile("s_waitcnt lgkmcnt(0)" ::: "memory");
        __builtin_amdgcn_sched_barrier(0);
        #pragma unroll
        for (int t = 0; t < 16; ++t) GDN_STEP(t);
        GDN_FLUSH(c * RCT);

        // ---- sub-chunk 1 ----
        RdKQ<0>::go(kv, qv, (lds_cfp)&ks[cur][16][e0], (lds_cfp)&qs[cur][16][e0]);
        RdVAB<0>::go(vv, av, bvr, (lds_cfp)&vs_t[cur][rl][16],
                     (lds_cfp)&gab_t[cur][0][16]);
        asm volatile("s_waitcnt lgkmcnt(0)" ::: "memory");
        __builtin_amdgcn_sched_barrier(0);
        #pragma unroll
        for (int t = 0; t < 16; ++t) GDN_STEP(t);
        GDN_FLUSH(c * RCT + 16);

        // commit v/ab prefetch into next buffer (transposed), then publish
        if (more) {
            if (lane < RCT) {
                vs_t[nxt][0][lane] = pv.x;
                vs_t[nxt][1][lane] = pv.y;
                vs_t[nxt][2][lane] = pv.z;
                vs_t[nxt][3][lane] = pv.w;
            }
            if (lane < 32) gab_t[nxt][0][lane] = pab;
            else           gab_t[nxt][1][lane - 32] = pab;
        }
        __syncthreads();
    }
}

// ---------------------------------------------------------------------------
// Fused: residual depthwise causal conv (bug-compat reshaped view) +
// transpose back + f16 convert (hi only) for the out-projection A matrix.
// ---------------------------------------------------------------------------
__global__ __launch_bounds__(256) void conv_convert(
    const float* __restrict__ att, const float* __restrict__ Wconv,
    _Float16* __restrict__ Ae2)
{
    __shared__ float yt[112][68];
    const int lb = blockIdx.x;
    const int h  = blockIdx.y;
    const int b  = blockIdx.z;
    const int tid = threadIdx.x;

    {
        const int d = tid >> 2;
        const int part = tid & 3;
        const float* src  = att + ((size_t)(b * NH + h) * DD + d) * LL;
        const float* srcm = src - (size_t)DD * LL;
        #pragma unroll
        for (int m = 0; m < 7; ++m) {
            const int off = (part * 7 + m) * 4;
            const int lg = lb * 64 - 48 + off;
            float4 v;
            if (lg >= 0)      v = *(const float4*)(src + lg);
            else if (h > 0)   v = *(const float4*)(srcm + lg + 1024);
            else              v = make_float4(0.f, 0.f, 0.f, 0.f);
            yt[off + 0][d] = v.x; yt[off + 1][d] = v.y;
            yt[off + 2][d] = v.z; yt[off + 3][d] = v.w;
        }
    }
    __syncthreads();

    float4 w[4];
    #pragma unroll
    for (int k = 0; k < 4; ++k)
        w[k] = ((const float4*)Wconv)[tid * 4 + k];

    const int d0 = (tid & 15) * 4;
    const int lq = tid >> 4;
    const float sc = 1.f / 4096.f;

    #pragma unroll
    for (int rr = 0; rr < 4; ++rr) {
        const int ll = rr * 16 + lq;
        float y0[4], y1[4], y2[4], y3[4];
        *(float4*)y0 = *(const float4*)&yt[ll +  0][d0];
        *(float4*)y1 = *(const float4*)&yt[ll + 16][d0];
        *(float4*)y2 = *(const float4*)&yt[ll + 32][d0];
        *(float4*)y3 = *(const float4*)&yt[ll + 48][d0];
        f16x4 hi;
        #pragma unroll
        for (int k = 0; k < 4; ++k) {
            float acc = y3[k];
            acc = fmaf(w[k].x, y0[k], acc);
            acc = fmaf(w[k].y, y1[k], acc);
            acc = fmaf(w[k].z, y2[k], acc);
            acc = fmaf(w[k].w, y3[k], acc);
            hi[k] = (_Float16)(acc * sc);
        }
        const size_t row = (size_t)b * 1024 + h * 64 + lb * 4 + rr;
        *(f16x4*)(Ae2 + row * 1024 + tid * 4) = hi;
    }
}

// ---------------------------------------------------------------------------
extern "C" void kernel_launch(void* const* d_in, const int* in_sizes, int n_in,
                              void* d_out, int out_size, void* d_ws, size_t ws_size,
                              hipStream_t stream)
{
    const float* hs    = (const float*)d_in[0];
    const float* Wq    = (const float*)d_in[1];
    const float* bq    = (const float*)d_in[2];
    const float* Wk    = (const float*)d_in[3];
    const float* bk    = (const float*)d_in[4];
    const float* Wv    = (const float*)d_in[5];
    const float* bv    = (const float*)d_in[6];
    const float* Wa    = (const float*)d_in[7];
    const float* Wb    = (const float*)d_in[8];
    const float* Wconv = (const float*)d_in[9];
    const float* Wo    = (const float*)d_in[10];
    const float* bo    = (const float*)d_in[11];
    float* out = (float*)d_out;

    // workspace layout (~63 MB)
    char* w = (char*)d_ws;
    float* qkv = (float*)w;        w += (size_t)MM * 3072 * 4;      // 25.2 MB
    float* att = (float*)w;        w += (size_t)MM * 1024 * 4;      //  8.4 MB ([B][NH][D][L])
    float* ab  = (float*)w;        w += (size_t)MM * 32 * 4;        //  0.26 MB
    _Float16* Ae3 = (_Float16*)w;  w += (size_t)MM * KEXT * 2;      // 12.6 MB
    _Float16* Bk  = (_Float16*)w;  w += (size_t)NBK * KEXT * 2;     //  6.7 MB
    _Float16* Bqv = (_Float16*)w;  w += (size_t)2048 * 1024 * 2;    //  4.2 MB
    _Float16* Ae2 = (_Float16*)w;  w += (size_t)MM * 1024 * 2;      //  4.2 MB
    _Float16* Be2 = (_Float16*)w;  w += (size_t)1024 * 1024 * 2;    //  2.1 MB

    // 1) conversions (hs->Ae3, Wk/Wa/Wb->Bk, Wq|Wv->Bqv, Wo->Be2)
    hipLaunchKernelGGL(convert_front, dim3(6208), dim3(256), 0, stream,
                       hs, Wq, Wk, Wv, Wa, Wb, Wo, Ae3, Bk, Bqv, Be2);

    // 2) merged projection GEMM (k+ab 272 blocks | q+v 256 blocks)
    hipLaunchKernelGGL(mfma_gemm_proj, dim3(528), dim3(256), 0, stream,
                       Ae3, Bk, Bqv, qkv, ab, bq, bk, bv);

    // 3) gated delta recurrence (r16: deferred output reductions)
    hipLaunchKernelGGL(gdn_recurrence, dim3(512), dim3(64), 0, stream, qkv, ab, att);

    // 4) fused conv + transpose + f16 convert (hi only, writes Ae2)
    hipLaunchKernelGGL(conv_convert, dim3(16, 16, BB), dim3(256), 0, stream,
                       att, Wconv, Ae2);

    // 5) out-projection (plain f16, K=1024, 128x64 tiles -> 256 blocks)
    hipLaunchKernelGGL(mfma_gemm_out, dim3(1024 / 64, MM / 128), dim3(256), 0, stream,
                       Ae2, Be2, out, bo);
}

// Round 5
// 280.059 us; speedup vs baseline: 1.0514x; 1.0046x over previous
//
#include <hip/hip_runtime.h>
#include <math.h>

// Problem constants
#define BB 2
#define LL 1024
#define HH 1024
#define NH 16
#define DD 64
#define HD (NH * DD)   // 1024
#define MM (BB * LL)   // 2048
#define RCT 32         // recurrence chunk length staged in LDS
#define KEXT 3072      // extended K for f16 hi/lo split GEMM (3 x 1024)
#define NBK 1088       // k-GEMM B rows: 1024 k + 16 alpha + 16 beta + 32 pad

typedef _Float16 f16x8 __attribute__((ext_vector_type(8)));
typedef _Float16 f16x4 __attribute__((ext_vector_type(4)));
typedef float f32x4 __attribute__((ext_vector_type(4)));

// ---------------------------------------------------------------------------
// async global->LDS, 16B per lane; LDS dest = wave-uniform base + lane*16
// ---------------------------------------------------------------------------
__device__ __forceinline__ void load_lds16(const void* g, void* l) {
    __builtin_amdgcn_global_load_lds(
        (const __attribute__((address_space(1))) void*)g,
        (__attribute__((address_space(3))) void*)l, 16, 0, 0);
}

// ---------------------------------------------------------------------------
// Conversions. Only k/alpha/beta compound through the recurrence -> 3-split
// f16 (K=3072); q (readout) and v (additive) are plain f16 and read the hi
// section of Ae3 directly (row stride KEXT) — no separate Ah copy.
//   blocks [0,2048):        hs -> Ae3 (x16, [hi|lo|hi])
//   blocks [2048,3136):     Wk/Wa/Wb -> Bk (x64, [hi|hi|lo]), rows>=1056 zero
//   blocks [3136,5184):     Wq|Wv -> Bqv (x64, hi only)
//   blocks [5184,6208):     Wo -> Be2 (x64, hi only)
// ---------------------------------------------------------------------------
__global__ __launch_bounds__(256) void convert_front(
    const float* __restrict__ hs,
    const float* __restrict__ Wq, const float* __restrict__ Wk,
    const float* __restrict__ Wv, const float* __restrict__ Wa,
    const float* __restrict__ Wb, const float* __restrict__ Wo,
    _Float16* __restrict__ Ae3,
    _Float16* __restrict__ Bk, _Float16* __restrict__ Bqv,
    _Float16* __restrict__ Be2)
{
    const int blk = blockIdx.x;
    const int t = threadIdx.x;

    if (blk < 2048) {             // hs -> Ae3 (3-split)
        float4 x = *(const float4*)(hs + (size_t)blk * 1024 + t * 4);
        x.x *= 16.f; x.y *= 16.f; x.z *= 16.f; x.w *= 16.f;
        f16x4 h, l;
        h[0] = (_Float16)x.x; l[0] = (_Float16)(x.x - (float)h[0]);
        h[1] = (_Float16)x.y; l[1] = (_Float16)(x.y - (float)h[1]);
        h[2] = (_Float16)x.z; l[2] = (_Float16)(x.z - (float)h[2]);
        h[3] = (_Float16)x.w; l[3] = (_Float16)(x.w - (float)h[3]);
        _Float16* base = Ae3 + (size_t)blk * KEXT + t * 4;
        *(f16x4*)(base)        = h;
        *(f16x4*)(base + 1024) = l;
        *(f16x4*)(base + 2048) = h;
        return;
    }
    if (blk < 3136) {             // Wk/Wa/Wb -> Bk (3-split, B-order)
        const int n = blk - 2048;
        const float* src = nullptr;
        if (n < 1024)      src = Wk + (size_t)n * 1024;
        else if (n < 1040) src = Wa + (size_t)(n - 1024) * 1024;
        else if (n < 1056) src = Wb + (size_t)(n - 1040) * 1024;
        float4 x = src ? *(const float4*)(src + t * 4)
                       : make_float4(0.f, 0.f, 0.f, 0.f);
        x.x *= 64.f; x.y *= 64.f; x.z *= 64.f; x.w *= 64.f;
        f16x4 h, l;
        h[0] = (_Float16)x.x; l[0] = (_Float16)(x.x - (float)h[0]);
        h[1] = (_Float16)x.y; l[1] = (_Float16)(x.y - (float)h[1]);
        h[2] = (_Float16)x.z; l[2] = (_Float16)(x.z - (float)h[2]);
        h[3] = (_Float16)x.w; l[3] = (_Float16)(x.w - (float)h[3]);
        _Float16* base = Bk + (size_t)n * KEXT + t * 4;
        *(f16x4*)(base)        = h;
        *(f16x4*)(base + 1024) = h;
        *(f16x4*)(base + 2048) = l;
        return;
    }
    if (blk < 5184) {             // Wq|Wv -> Bqv (hi only)
        const int n = blk - 3136;
        const float* src = (n < 1024) ? Wq + (size_t)n * 1024
                                      : Wv + (size_t)(n - 1024) * 1024;
        float4 x = *(const float4*)(src + t * 4);
        f16x4 h;
        h[0] = (_Float16)(x.x * 64.f);
        h[1] = (_Float16)(x.y * 64.f);
        h[2] = (_Float16)(x.z * 64.f);
        h[3] = (_Float16)(x.w * 64.f);
        *(f16x4*)(Bqv + (size_t)n * 1024 + t * 4) = h;
        return;
    }
    {                             // Wo -> Be2 (hi only)
        const int n = blk - 5184;
        float4 x = *(const float4*)(Wo + (size_t)n * 1024 + t * 4);
        f16x4 h;
        h[0] = (_Float16)(x.x * 64.f);
        h[1] = (_Float16)(x.y * 64.f);
        h[2] = (_Float16)(x.z * 64.f);
        h[3] = (_Float16)(x.w * 64.f);
        *(f16x4*)(Be2 + (size_t)n * 1024 + t * 4) = h;
    }
}

// ---------------------------------------------------------------------------
// MERGED projection GEMM: 528 blocks.
//   blk <  272: k+ab part — Ae3 @ Bk^T, K=3072, 128x64 tile (17 N-tiles).
//   blk >= 272: q|v part  — Ae3-hi @ Bqv^T, K=1024, 128x128 tile (A row
//               stride KEXT, hi section).
// ---------------------------------------------------------------------------
__global__ __launch_bounds__(256) void mfma_gemm_proj(
    const _Float16* __restrict__ Ae3, const _Float16* __restrict__ Bk,
    const _Float16* __restrict__ Bqv,
    float* __restrict__ qkv, float* __restrict__ ab,
    const float* __restrict__ bq, const float* __restrict__ bk,
    const float* __restrict__ bv)
{
    __shared__ __align__(16) _Float16 As[2][128 * 32];
    __shared__ __align__(16) _Float16 Bs[2][128 * 32];

    const int blk = blockIdx.x;
    const int tid = threadIdx.x;
    const int wave = tid >> 6;
    const int lane = tid & 63;
    const int srow = lane >> 2;
    const int scol = (lane & 3) * 8;
    const int fm = lane & 15;
    const int fq = (lane >> 4) * 8;
    const int rquad = (lane >> 4) * 4;

    if (blk < 272) {
        const int bm = (blk / 17) * 128;
        const int bn = (blk % 17) * 64;
        const int wr = (wave >> 1) * 64;
        const int wc = (wave & 1) * 32;

        const _Float16* gA0 = Ae3 + (size_t)(bm + wave * 32 + srow) * KEXT + scol;
        const _Float16* gA1 = gA0 + (size_t)16 * KEXT;
        const _Float16* gB0 = Bk + (size_t)(bn + wave * 16 + srow) * KEXT + scol;
        _Float16* lA0_0 = &As[0][(wave * 32) * 32];
        _Float16* lA1_0 = &As[0][(wave * 32 + 16) * 32];
        _Float16* lB0_0 = &Bs[0][(wave * 16) * 32];
        _Float16* lA0_1 = &As[1][(wave * 32) * 32];
        _Float16* lA1_1 = &As[1][(wave * 32 + 16) * 32];
        _Float16* lB0_1 = &Bs[1][(wave * 16) * 32];

        f32x4 acc[4][2] = {};

        for (int k0 = 0; k0 < KEXT; k0 += 64) {
            load_lds16(gA0 + k0,      lA0_0);
            load_lds16(gA1 + k0,      lA1_0);
            load_lds16(gB0 + k0,      lB0_0);
            load_lds16(gA0 + k0 + 32, lA0_1);
            load_lds16(gA1 + k0 + 32, lA1_1);
            load_lds16(gB0 + k0 + 32, lB0_1);
            __syncthreads();

            #pragma unroll
            for (int s = 0; s < 2; ++s) {
                f16x8 a[4], b[2];
                #pragma unroll
                for (int mt = 0; mt < 4; ++mt)
                    a[mt] = *(const f16x8*)&As[s][(wr + mt * 16 + fm) * 32 + fq];
                #pragma unroll
                for (int nt = 0; nt < 2; ++nt)
                    b[nt] = *(const f16x8*)&Bs[s][(wc + nt * 16 + fm) * 32 + fq];
                #pragma unroll
                for (int mt = 0; mt < 4; ++mt)
                    #pragma unroll
                    for (int nt = 0; nt < 2; ++nt)
                        acc[mt][nt] = __builtin_amdgcn_mfma_f32_16x16x32_f16(
                            a[mt], b[nt], acc[mt][nt], 0, 0, 0);
            }
            __syncthreads();
        }

        #pragma unroll
        for (int mt = 0; mt < 4; ++mt) {
            #pragma unroll
            for (int nt = 0; nt < 2; ++nt) {
                const int col = bn + wc + nt * 16 + fm;
                #pragma unroll
                for (int i = 0; i < 4; ++i) {
                    const int row = bm + wr + mt * 16 + rquad + i;
                    float val = acc[mt][nt][i] * (1.0f / 1024.0f);
                    if (col < 1024)
                        qkv[(size_t)row * 3072 + 1024 + col] = val + bk[col];
                    else if (col < 1040)
                        ab[(size_t)row * 32 + (col - 1024)] =
                            1.f / (1.f + expf(-val));
                    else if (col < 1056)
                        ab[(size_t)row * 32 + 16 + (col - 1040)] =
                            fmaxf(val, 0.f) + log1pf(expf(-fabsf(val)));
                }
            }
        }
    } else {
        const int n = blk - 272;
        const int bm = (n / 16) * 128;
        const int bn = (n % 16) * 128;
        const int wr = (wave >> 1) * 64;
        const int wc = (wave & 1) * 64;

        // A = hi section of Ae3, row stride KEXT
        const _Float16* gA0 = Ae3 + (size_t)(bm + wave * 32 + srow) * KEXT + scol;
        const _Float16* gA1 = gA0 + (size_t)16 * KEXT;
        const _Float16* gB0 = Bqv + (size_t)(bn + wave * 32 + srow) * 1024 + scol;
        const _Float16* gB1 = gB0 + (size_t)16 * 1024;
        _Float16* lA0_0 = &As[0][(wave * 32) * 32];
        _Float16* lA1_0 = &As[0][(wave * 32 + 16) * 32];
        _Float16* lB0_0 = &Bs[0][(wave * 32) * 32];
        _Float16* lB1_0 = &Bs[0][(wave * 32 + 16) * 32];
        _Float16* lA0_1 = &As[1][(wave * 32) * 32];
        _Float16* lA1_1 = &As[1][(wave * 32 + 16) * 32];
        _Float16* lB0_1 = &Bs[1][(wave * 32) * 32];
        _Float16* lB1_1 = &Bs[1][(wave * 32 + 16) * 32];

        f32x4 acc[4][4] = {};

        for (int k0 = 0; k0 < 1024; k0 += 64) {
            load_lds16(gA0 + k0,      lA0_0);
            load_lds16(gA1 + k0,      lA1_0);
            load_lds16(gB0 + k0,      lB0_0);
            load_lds16(gB1 + k0,      lB1_0);
            load_lds16(gA0 + k0 + 32, lA0_1);
            load_lds16(gA1 + k0 + 32, lA1_1);
            load_lds16(gB0 + k0 + 32, lB0_1);
            load_lds16(gB1 + k0 + 32, lB1_1);
            __syncthreads();

            #pragma unroll
            for (int s = 0; s < 2; ++s) {
                f16x8 a[4], b[4];
                #pragma unroll
                for (int mt = 0; mt < 4; ++mt)
                    a[mt] = *(const f16x8*)&As[s][(wr + mt * 16 + fm) * 32 + fq];
                #pragma unroll
                for (int nt = 0; nt < 4; ++nt)
                    b[nt] = *(const f16x8*)&Bs[s][(wc + nt * 16 + fm) * 32 + fq];
                #pragma unroll
                for (int mt = 0; mt < 4; ++mt)
                    #pragma unroll
                    for (int nt = 0; nt < 4; ++nt)
                        acc[mt][nt] = __builtin_amdgcn_mfma_f32_16x16x32_f16(
                            a[mt], b[nt], acc[mt][nt], 0, 0, 0);
            }
            __syncthreads();
        }

        #pragma unroll
        for (int mt = 0; mt < 4; ++mt) {
            #pragma unroll
            for (int nt = 0; nt < 4; ++nt) {
                const int col = bn + wc + nt * 16 + fm;
                #pragma unroll
                for (int i = 0; i < 4; ++i) {
                    const int row = bm + wr + mt * 16 + rquad + i;
                    float val = acc[mt][nt][i] * (1.0f / 1024.0f);
                    if (col < 1024)
                        qkv[(size_t)row * 3072 + col] = val + bq[col];
                    else
                        qkv[(size_t)row * 3072 + 1024 + col] = val + bv[col - 1024];
                }
            }
        }
    }
}

// ---------------------------------------------------------------------------
// Out-projection MFMA GEMM (unchanged): plain f16, K=1024, 128x64, BK=64.
// ---------------------------------------------------------------------------
__global__ __launch_bounds__(256) void mfma_gemm_out(
    const _Float16* __restrict__ Ae2, const _Float16* __restrict__ Be2,
    float* __restrict__ outp, const float* __restrict__ bo)
{
    __shared__ __align__(16) _Float16 As[2][128 * 32];
    __shared__ __align__(16) _Float16 Bs[2][64 * 32];

    const int tid = threadIdx.x;
    const int wave = tid >> 6;
    const int lane = tid & 63;
    const int bm = blockIdx.y * 128;
    const int bn = blockIdx.x * 64;
    const int wr = (wave >> 1) * 64;
    const int wc = (wave & 1) * 32;

    const int srow = lane >> 2;
    const int scol = (lane & 3) * 8;
    const _Float16* gA0 = Ae2 + (size_t)(bm + wave * 32 + srow) * 1024 + scol;
    const _Float16* gA1 = gA0 + (size_t)16 * 1024;
    const _Float16* gB0 = Be2 + (size_t)(bn + wave * 16 + srow) * 1024 + scol;
    _Float16* lA0_0 = &As[0][(wave * 32) * 32];
    _Float16* lA1_0 = &As[0][(wave * 32 + 16) * 32];
    _Float16* lB0_0 = &Bs[0][(wave * 16) * 32];
    _Float16* lA0_1 = &As[1][(wave * 32) * 32];
    _Float16* lA1_1 = &As[1][(wave * 32 + 16) * 32];
    _Float16* lB0_1 = &Bs[1][(wave * 16) * 32];

    const int fm = lane & 15;
    const int fq = (lane >> 4) * 8;

    f32x4 acc[4][2] = {};

    for (int k0 = 0; k0 < 1024; k0 += 64) {
        load_lds16(gA0 + k0,      lA0_0);
        load_lds16(gA1 + k0,      lA1_0);
        load_lds16(gB0 + k0,      lB0_0);
        load_lds16(gA0 + k0 + 32, lA0_1);
        load_lds16(gA1 + k0 + 32, lA1_1);
        load_lds16(gB0 + k0 + 32, lB0_1);
        __syncthreads();

        #pragma unroll
        for (int s = 0; s < 2; ++s) {
            f16x8 a[4], b[2];
            #pragma unroll
            for (int mt = 0; mt < 4; ++mt)
                a[mt] = *(const f16x8*)&As[s][(wr + mt * 16 + fm) * 32 + fq];
            #pragma unroll
            for (int nt = 0; nt < 2; ++nt)
                b[nt] = *(const f16x8*)&Bs[s][(wc + nt * 16 + fm) * 32 + fq];
            #pragma unroll
            for (int mt = 0; mt < 4; ++mt)
                #pragma unroll
                for (int nt = 0; nt < 2; ++nt)
                    acc[mt][nt] = __builtin_amdgcn_mfma_f32_16x16x32_f16(
                        a[mt], b[nt], acc[mt][nt], 0, 0, 0);
        }
        __syncthreads();
    }

    const int rquad = (lane >> 4) * 4;
    #pragma unroll
    for (int mt = 0; mt < 4; ++mt) {
        #pragma unroll
        for (int nt = 0; nt < 2; ++nt) {
            const int col = bn + wc + nt * 16 + fm;
            #pragma unroll
            for (int i = 0; i < 4; ++i) {
                const int row = bm + wr + mt * 16 + rquad + i;
                outp[(size_t)row * 1024 + col] = acc[mt][nt][i] * 64.f + bo[col];
            }
        }
    }
}

// ---------------------------------------------------------------------------
// DPP 16-lane reductions. red16x4: 4 interleaved independent chains.
// ---------------------------------------------------------------------------
template <int CTRL>
__device__ __forceinline__ float dpp_addf(float x) {
    int y = __builtin_amdgcn_update_dpp(0, __builtin_bit_cast(int, x),
                                        CTRL, 0xF, 0xF, true);
    return x + __builtin_bit_cast(float, y);
}
__device__ __forceinline__ void red16x4(float& x0, float& x1,
                                        float& x2, float& x3) {
    x0 = dpp_addf<0xB1>(x0);  x1 = dpp_addf<0xB1>(x1);
    x2 = dpp_addf<0xB1>(x2);  x3 = dpp_addf<0xB1>(x3);
    x0 = dpp_addf<0x4E>(x0);  x1 = dpp_addf<0x4E>(x1);
    x2 = dpp_addf<0x4E>(x2);  x3 = dpp_addf<0x4E>(x3);
    x0 = dpp_addf<0x124>(x0); x1 = dpp_addf<0x124>(x1);
    x2 = dpp_addf<0x124>(x2); x3 = dpp_addf<0x124>(x3);
    x0 = dpp_addf<0x128>(x0); x1 = dpp_addf<0x128>(x1);
    x2 = dpp_addf<0x128>(x2); x3 = dpp_addf<0x128>(x3);
}

// ---------------------------------------------------------------------------
// Pair prepass: data-only dot products over the 64-dim head slice, consumed
// by the pairwise-cascade recurrence. For each (b,h) chain and pair p
// (t = 2p): Pq[bh][p] = { k_t.k_{t+1}, k_t.q_t, k_t.q_{t+1}, k_{t+1}.q_{t+1} }.
// 1024 blocks x 64 threads; 16-lane e-slices x 4 pair-rows per wave.
// ---------------------------------------------------------------------------
__global__ __launch_bounds__(64) void pair_prepass(
    const float* __restrict__ qkv, float* __restrict__ Pq)
{
    const int blk = blockIdx.x;        // 32 bh * 32 seg
    const int bh = blk >> 5;
    const int seg = blk & 31;          // 16 pairs per seg
    const int b = bh >> 4, h = bh & 15;
    const int lane = threadIdx.x;
    const int rl = lane >> 4;
    const int el = lane & 15;
    const int e0 = el * 4;
    const float* qb = qkv + (size_t)b * LL * 3072 + h * 64;
    const float* kb = qb + 1024;

    #pragma unroll
    for (int pp_ = 0; pp_ < 4; ++pp_) {
        const int p = seg * 16 + pp_ * 4 + rl;
        const int t = 2 * p;
        const float4 kA = *(const float4*)(kb + (size_t)t * 3072 + e0);
        const float4 kB = *(const float4*)(kb + (size_t)(t + 1) * 3072 + e0);
        const float4 qA = *(const float4*)(qb + (size_t)t * 3072 + e0);
        const float4 qB = *(const float4*)(qb + (size_t)(t + 1) * 3072 + e0);
        float kk  = fmaf(kA.y, kB.y, kA.x * kB.x) + fmaf(kA.w, kB.w, kA.z * kB.z);
        float kqA = fmaf(kA.y, qA.y, kA.x * qA.x) + fmaf(kA.w, qA.w, kA.z * qA.z);
        float kqB = fmaf(kA.y, qB.y, kA.x * qB.x) + fmaf(kA.w, qB.w, kA.z * qB.z);
        float kqC = fmaf(kB.y, qB.y, kB.x * qB.x) + fmaf(kB.w, qB.w, kB.z * qB.z);
        red16x4(kk, kqA, kqB, kqC);
        if (el == 0)
            *(float4*)(Pq + ((size_t)bh * 512 + p) * 4) =
                make_float4(kk, kqA, kqB, kqC);
    }
}

// ---------------------------------------------------------------------------
// r15-style pinned LDS->reg bursts (inline-asm volatile ds_read_b128, cannot
// be sunk); one lgkmcnt(0)+sched_barrier(0) per burst, then pure-register
// compute. r17: the compute is the PAIRWISE CASCADE.
// ---------------------------------------------------------------------------
typedef __attribute__((address_space(3))) const float* lds_cfp;

__device__ __forceinline__ float4 ds_read_f4(lds_cfp p) {
    float4 d;
    asm volatile("ds_read_b128 %0, %1" : "=v"(d) : "v"(p));
    return d;
}

template <int I> struct RdKQ {
    static __device__ __forceinline__ void go(float4* k, float4* q,
                                              lds_cfp kb, lds_cfp qb) {
        k[I] = ds_read_f4(kb + I * 64);   // row stride 64 floats (256 B)
        q[I] = ds_read_f4(qb + I * 64);
        RdKQ<I + 1>::go(k, q, kb, qb);
    }
};
template <> struct RdKQ<16> {
    static __device__ __forceinline__ void go(float4*, float4*, lds_cfp, lds_cfp) {}
};

template <int I> struct RdVAB {
    static __device__ __forceinline__ void go(float4* v, float4* a, float4* b,
                                              lds_cfp vb, lds_cfp abb) {
        v[I] = ds_read_f4(vb + I * 4);          // 4 consecutive timesteps
        a[I] = ds_read_f4(abb + I * 4);         // a-row
        b[I] = ds_read_f4(abb + RCT + I * 4);   // b-row (+RCT floats)
        RdVAB<I + 1>::go(v, a, b, vb, abb);
    }
};
template <> struct RdVAB<4> {
    static __device__ __forceinline__ void go(float4*, float4*, float4*, lds_cfp, lds_cfp) {}
};

template <int I> struct RdP {
    static __device__ __forceinline__ void go(float4* p, lds_cfp pb) {
        p[I] = ds_read_f4(pb + I * 4);          // broadcast (uniform addr)
        RdP<I + 1>::go(p, pb);
    }
};
template <> struct RdP<8> {
    static __device__ __forceinline__ void go(float4*, lds_cfp) {}
};

// ---------------------------------------------------------------------------
// r17 pairwise cascade. Exact algebra of two r11 steps, restructured so ONE
// carried-chain traversal covers TWO timesteps (r16 post-mortem: per removed
// walk-instruction saving ~3.3 cy; the binder is walk LEVELS per step — 15.
// Pairwise: 18 levels / 2 steps = 9/step).
//   base reds (pre-pair S, 4 interleaved): skA=S.k, skB=S.k', sqA=S.q, sqB=S.q'
//   cf  = b (v - a skA)
//   sk' = S_t.k' = a skB + cf kk              [kk from prepass]
//   cf' = b'(v' - a' sk')
//   S   = a'(a S + cf k) + cf' k'
//   o_t   = a sqA + cf kqA                    [fully-reduced scalar]
//   o_t+1 = a'(a sqB + cf kqB) + cf' kqC
// DPP count per step unchanged (2 red16/step); no output reductions at all.
// ---------------------------------------------------------------------------
#define GDN_PAIR(P)                                                     \
    {                                                                   \
        const float4 k1 = kv[2 * (P)];                                  \
        const float4 k2 = kv[2 * (P) + 1];                              \
        const float4 q1 = qv[2 * (P)];                                  \
        const float4 q2 = qv[2 * (P) + 1];                              \
        const float v1 = vv[(P) >> 1][(2 * (P)) & 3];                   \
        const float v2 = vv[(P) >> 1][(2 * (P) + 1) & 3];               \
        const float a1 = av[(P) >> 1][(2 * (P)) & 3];                   \
        const float a2 = av[(P) >> 1][(2 * (P) + 1) & 3];               \
        const float b1 = bvr[(P) >> 1][(2 * (P)) & 3];                  \
        const float b2 = bvr[(P) >> 1][(2 * (P) + 1) & 3];              \
        const float4 pp = pv4[P];                                       \
        float skA = fmaf(S1, k1.y, S0 * k1.x) + fmaf(S3, k1.w, S2 * k1.z); \
        float skB = fmaf(S1, k2.y, S0 * k2.x) + fmaf(S3, k2.w, S2 * k2.z); \
        float sqA = fmaf(S1, q1.y, S0 * q1.x) + fmaf(S3, q1.w, S2 * q1.z); \
        float sqB = fmaf(S1, q2.y, S0 * q2.x) + fmaf(S3, q2.w, S2 * q2.z); \
        const float aS0 = a1 * S0, aS1 = a1 * S1;                       \
        const float aS2 = a1 * S2, aS3 = a1 * S3;                       \
        red16x4(skA, skB, sqA, sqB);                                    \
        const float cf = b1 * fmaf(-a1, skA, v1);                       \
        const float sk2 = fmaf(cf, pp.x, a1 * skB);                     \
        const float cf2 = b2 * fmaf(-a2, sk2, v2);                      \
        const float T0 = fmaf(cf, k1.x, aS0);                           \
        const float T1 = fmaf(cf, k1.y, aS1);                           \
        const float T2 = fmaf(cf, k1.z, aS2);                           \
        const float T3 = fmaf(cf, k1.w, aS3);                           \
        S0 = fmaf(cf2, k2.x, a2 * T0);                                  \
        S1 = fmaf(cf2, k2.y, a2 * T1);                                  \
        S2 = fmaf(cf2, k2.z, a2 * T2);                                  \
        S3 = fmaf(cf2, k2.w, a2 * T3);                                  \
        qp[2 * (P)] = fmaf(cf, pp.y, a1 * sqA);                         \
        const float inn = fmaf(cf, pp.z, a1 * sqB);                     \
        qp[2 * (P) + 1] = fmaf(cf2, pp.w, a2 * inn);                    \
    }

#define GDN_STORE(TBASE)                                                \
    if (el == 0) {                                                      \
        *(float4*)(op + (TBASE) + 0)  = make_float4(qp[0],  qp[1],  qp[2],  qp[3]);  \
        *(float4*)(op + (TBASE) + 4)  = make_float4(qp[4],  qp[5],  qp[6],  qp[7]);  \
        *(float4*)(op + (TBASE) + 8)  = make_float4(qp[8],  qp[9],  qp[10], qp[11]); \
        *(float4*)(op + (TBASE) + 12) = make_float4(qp[12], qp[13], qp[14], qp[15]); \
    }

// ---------------------------------------------------------------------------
// Gated delta recurrence — r17. r15/r16 staging/burst structure; inner loop
// replaced by the pairwise cascade (8 pairs per 16-step run). Pair scalars
// (kk,kqA,kqB,kqC) staged from the prepass array like ab.
// 512 blocks x 64 threads; blk%32 = chain (XCD co-location), blk/32 = 4-row
// slice. Global->LDS staging (async, double-buffered) unchanged from r11.
// ---------------------------------------------------------------------------
__global__ __launch_bounds__(64) void gdn_recurrence(
    const float* __restrict__ qkv, const float* __restrict__ ab,
    const float* __restrict__ Pq, float* __restrict__ att)
{
    __shared__ __align__(16) float ks[2][RCT][64];
    __shared__ __align__(16) float qs[2][RCT][64];
    __shared__ __align__(16) float vs_t[2][4][RCT];   // [buf][row][t]
    __shared__ __align__(16) float gab_t[2][2][RCT];  // [buf][a/b][t]
    __shared__ __align__(16) float ps[2][16][4];      // [buf][pair][4 scalars]

    const int blk = blockIdx.x;
    const int bh = blk & 31;          // chain (XCD co-location)
    const int s  = blk >> 5;          // row-slice 0..15
    const int b  = bh >> 4;
    const int h  = bh & 15;
    const int lane = threadIdx.x;
    const int rl = lane >> 4;         // local row 0..3
    const int el = lane & 15;         // e-slice
    const int e0 = el * 4;
    const int r0 = s * 4;

    const float* qb  = qkv + (size_t)b * LL * 3072 + h * 64;
    const float* kb  = qb + 1024;
    const float* vb  = qb + 2048 + r0;
    const float* abp = ab + (size_t)b * LL * 32 + h;
    const float* Pg  = Pq + (size_t)bh * 512 * 4;
    float* op = att + ((size_t)(b * NH + h) * DD + r0 + rl) * LL;

    const int st = lane >> 4;          // t-within-4 for staging
    const int sd = (lane & 15) * 4;    // d offset

    float S0 = 0.f, S1 = 0.f, S2 = 0.f, S3 = 0.f;

    // ---- async-stage k/q/pair chunk 0, reg-load v/ab chunk 0 ----
    {
        const size_t ro = (size_t)st * 3072 + sd;
        #pragma unroll
        for (int m = 0; m < 8; ++m) {
            load_lds16(kb + ro + (size_t)m * 4 * 3072, &ks[0][m * 4][0]);
            load_lds16(qb + ro + (size_t)m * 4 * 3072, &qs[0][m * 4][0]);
        }
        if (lane < 16) load_lds16(Pg + (size_t)lane * 4, &ps[0][0][0]);
        float4 pv = make_float4(0.f,0.f,0.f,0.f);
        if (lane < RCT) pv = *(const float4*)(vb + (size_t)lane * 3072);
        float pab = (lane < 32) ? abp[(size_t)lane * 32]
                                : abp[(size_t)(lane - 32) * 32 + 16];
        if (lane < RCT) {
            vs_t[0][0][lane] = pv.x;
            vs_t[0][1][lane] = pv.y;
            vs_t[0][2][lane] = pv.z;
            vs_t[0][3][lane] = pv.w;
        }
        if (lane < 32) gab_t[0][0][lane] = pab;
        else           gab_t[0][1][lane - 32] = pab;
    }
    __syncthreads();

    const int NCHUNK = LL / RCT;
    for (int c = 0; c < NCHUNK; ++c) {
        const int cur = c & 1, nxt = cur ^ 1;
        const bool more = (c + 1 < NCHUNK);

        // issue async staging for chunk c+1; tiny reg prefetch for v/ab
        float4 pv = make_float4(0.f,0.f,0.f,0.f);
        float pab = 0.f;
        if (more) {
            const size_t t0 = (size_t)(c + 1) * RCT;
            const size_t ro = (t0 + st) * 3072 + sd;
            #pragma unroll
            for (int m = 0; m < 8; ++m) {
                load_lds16(kb + ro + (size_t)m * 4 * 3072, &ks[nxt][m * 4][0]);
                load_lds16(qb + ro + (size_t)m * 4 * 3072, &qs[nxt][m * 4][0]);
            }
            if (lane < 16)
                load_lds16(Pg + (size_t)((c + 1) * 16 + lane) * 4,
                           &ps[nxt][0][0]);
            if (lane < RCT) pv = *(const float4*)(vb + (t0 + lane) * 3072);
            pab = (lane < 32) ? abp[(t0 + lane) * 32]
                              : abp[(t0 + lane - 32) * 32 + 16];
        }

        float4 kv[16], qv[16], vv[4], av[4], bvr[4], pv4[8];
        float qp[16];

        // ---- sub-chunk 0: pinned burst, 8 pure-register pairs, store ----
        RdKQ<0>::go(kv, qv, (lds_cfp)&ks[cur][0][e0], (lds_cfp)&qs[cur][0][e0]);
        RdVAB<0>::go(vv, av, bvr, (lds_cfp)&vs_t[cur][rl][0],
                     (lds_cfp)&gab_t[cur][0][0]);
        RdP<0>::go(pv4, (lds_cfp)&ps[cur][0][0]);
        asm volatile("s_waitcnt lgkmcnt(0)" ::: "memory");
        __builtin_amdgcn_sched_barrier(0);
        GDN_PAIR(0) GDN_PAIR(1) GDN_PAIR(2) GDN_PAIR(3)
        GDN_PAIR(4) GDN_PAIR(5) GDN_PAIR(6) GDN_PAIR(7)
        GDN_STORE(c * RCT);

        // ---- sub-chunk 1 ----
        RdKQ<0>::go(kv, qv, (lds_cfp)&ks[cur][16][e0], (lds_cfp)&qs[cur][16][e0]);
        RdVAB<0>::go(vv, av, bvr, (lds_cfp)&vs_t[cur][rl][16],
                     (lds_cfp)&gab_t[cur][0][16]);
        RdP<0>::go(pv4, (lds_cfp)&ps[cur][8][0]);
        asm volatile("s_waitcnt lgkmcnt(0)" ::: "memory");
        __builtin_amdgcn_sched_barrier(0);
        GDN_PAIR(0) GDN_PAIR(1) GDN_PAIR(2) GDN_PAIR(3)
        GDN_PAIR(4) GDN_PAIR(5) GDN_PAIR(6) GDN_PAIR(7)
        GDN_STORE(c * RCT + 16);

        // commit v/ab prefetch into next buffer (transposed), then publish
        if (more) {
            if (lane < RCT) {
                vs_t[nxt][0][lane] = pv.x;
                vs_t[nxt][1][lane] = pv.y;
                vs_t[nxt][2][lane] = pv.z;
                vs_t[nxt][3][lane] = pv.w;
            }
            if (lane < 32) gab_t[nxt][0][lane] = pab;
            else           gab_t[nxt][1][lane - 32] = pab;
        }
        __syncthreads();
    }
}

// ---------------------------------------------------------------------------
// Fused: residual depthwise causal conv (bug-compat reshaped view) +
// transpose back + f16 convert (hi only) for the out-projection A matrix.
// ---------------------------------------------------------------------------
__global__ __launch_bounds__(256) void conv_convert(
    const float* __restrict__ att, const float* __restrict__ Wconv,
    _Float16* __restrict__ Ae2)
{
    __shared__ float yt[112][68];
    const int lb = blockIdx.x;
    const int h  = blockIdx.y;
    const int b  = blockIdx.z;
    const int tid = threadIdx.x;

    {
        const int d = tid >> 2;
        const int part = tid & 3;
        const float* src  = att + ((size_t)(b * NH + h) * DD + d) * LL;
        const float* srcm = src - (size_t)DD * LL;
        #pragma unroll
        for (int m = 0; m < 7; ++m) {
            const int off = (part * 7 + m) * 4;
            const int lg = lb * 64 - 48 + off;
            float4 v;
            if (lg >= 0)      v = *(const float4*)(src + lg);
            else if (h > 0)   v = *(const float4*)(srcm + lg + 1024);
            else              v = make_float4(0.f, 0.f, 0.f, 0.f);
            yt[off + 0][d] = v.x; yt[off + 1][d] = v.y;
            yt[off + 2][d] = v.z; yt[off + 3][d] = v.w;
        }
    }
    __syncthreads();

    float4 w[4];
    #pragma unroll
    for (int k = 0; k < 4; ++k)
        w[k] = ((const float4*)Wconv)[tid * 4 + k];

    const int d0 = (tid & 15) * 4;
    const int lq = tid >> 4;
    const float sc = 1.f / 4096.f;

    #pragma unroll
    for (int rr = 0; rr < 4; ++rr) {
        const int ll = rr * 16 + lq;
        float y0[4], y1[4], y2[4], y3[4];
        *(float4*)y0 = *(const float4*)&yt[ll +  0][d0];
        *(float4*)y1 = *(const float4*)&yt[ll + 16][d0];
        *(float4*)y2 = *(const float4*)&yt[ll + 32][d0];
        *(float4*)y3 = *(const float4*)&yt[ll + 48][d0];
        f16x4 hi;
        #pragma unroll
        for (int k = 0; k < 4; ++k) {
            float acc = y3[k];
            acc = fmaf(w[k].x, y0[k], acc);
            acc = fmaf(w[k].y, y1[k], acc);
            acc = fmaf(w[k].z, y2[k], acc);
            acc = fmaf(w[k].w, y3[k], acc);
            hi[k] = (_Float16)(acc * sc);
        }
        const size_t row = (size_t)b * 1024 + h * 64 + lb * 4 + rr;
        *(f16x4*)(Ae2 + row * 1024 + tid * 4) = hi;
    }
}

// ---------------------------------------------------------------------------
extern "C" void kernel_launch(void* const* d_in, const int* in_sizes, int n_in,
                              void* d_out, int out_size, void* d_ws, size_t ws_size,
                              hipStream_t stream)
{
    const float* hs    = (const float*)d_in[0];
    const float* Wq    = (const float*)d_in[1];
    const float* bq    = (const float*)d_in[2];
    const float* Wk    = (const float*)d_in[3];
    const float* bk    = (const float*)d_in[4];
    const float* Wv    = (const float*)d_in[5];
    const float* bv    = (const float*)d_in[6];
    const float* Wa    = (const float*)d_in[7];
    const float* Wb    = (const float*)d_in[8];
    const float* Wconv = (const float*)d_in[9];
    const float* Wo    = (const float*)d_in[10];
    const float* bo    = (const float*)d_in[11];
    float* out = (float*)d_out;

    // workspace layout (~63.9 MB)
    char* w = (char*)d_ws;
    float* qkv = (float*)w;        w += (size_t)MM * 3072 * 4;      // 25.2 MB
    float* att = (float*)w;        w += (size_t)MM * 1024 * 4;      //  8.4 MB ([B][NH][D][L])
    float* ab  = (float*)w;        w += (size_t)MM * 32 * 4;        //  0.26 MB
    _Float16* Ae3 = (_Float16*)w;  w += (size_t)MM * KEXT * 2;      // 12.6 MB
    _Float16* Bk  = (_Float16*)w;  w += (size_t)NBK * KEXT * 2;     //  6.7 MB
    _Float16* Bqv = (_Float16*)w;  w += (size_t)2048 * 1024 * 2;    //  4.2 MB
    _Float16* Ae2 = (_Float16*)w;  w += (size_t)MM * 1024 * 2;      //  4.2 MB
    _Float16* Be2 = (_Float16*)w;  w += (size_t)1024 * 1024 * 2;    //  2.1 MB
    float* Pq  = (float*)w;        w += (size_t)32 * 512 * 4 * 4;   //  0.26 MB

    // 1) conversions (hs->Ae3, Wk/Wa/Wb->Bk, Wq|Wv->Bqv, Wo->Be2)
    hipLaunchKernelGGL(convert_front, dim3(6208), dim3(256), 0, stream,
                       hs, Wq, Wk, Wv, Wa, Wb, Wo, Ae3, Bk, Bqv, Be2);

    // 2) merged projection GEMM (k+ab 272 blocks | q+v 256 blocks)
    hipLaunchKernelGGL(mfma_gemm_proj, dim3(528), dim3(256), 0, stream,
                       Ae3, Bk, Bqv, qkv, ab, bq, bk, bv);

    // 2.5) pair prepass: data-only k/q dot products for the cascade
    hipLaunchKernelGGL(pair_prepass, dim3(1024), dim3(64), 0, stream, qkv, Pq);

    // 3) gated delta recurrence (r17: pairwise cascade, 9 walk-levels/step)
    hipLaunchKernelGGL(gdn_recurrence, dim3(512), dim3(64), 0, stream,
                       qkv, ab, Pq, att);

    // 4) fused conv + transpose + f16 convert (hi only, writes Ae2)
    hipLaunchKernelGGL(conv_convert, dim3(16, 16, BB), dim3(256), 0, stream,
                       att, Wconv, Ae2);

    // 5) out-projection (plain f16, K=1024, 128x64 tiles -> 256 blocks)
    hipLaunchKernelGGL(mfma_gemm_out, dim3(1024 / 64, MM / 128), dim3(256), 0, stream,
                       Ae2, Be2, out, bo);
}